// Round 1
// baseline (3535.265 us; speedup 1.0000x reference)
//
#include <hip/hip_runtime.h>
#include <hip/hip_bf16.h>

typedef __hip_bfloat16 bf16;

#define HH 270
#define WW 512
#define BB 4
#define HP 271
#define WP 513
#define NPIX (HH*WW)      // 138240
#define NPOOL (HP*WP)     // 139023
#define TWO_PI 6.28318530717958647692f

// ---------------------------------------------------------------------------
// Weight transpose: [O][CK] -> [CK][O] so the conv o-loop reads contiguous,
// thread-uniform floats (s_load_dwordx16 broadcast path).
__global__ void k_wprep(const float* __restrict__ w1, const float* __restrict__ w2,
                        const float* __restrict__ w3, float* __restrict__ wT1,
                        float* __restrict__ wT2, float* __restrict__ wT3) {
    int stride = gridDim.x * blockDim.x;
    int t0 = blockIdx.x * blockDim.x + threadIdx.x;
    for (int i = t0; i < 3200*32; i += stride) { int ck = i >> 5, o = i & 31; wT1[i] = w1[o*3200 + ck]; }
    for (int i = t0; i < 288*8;  i += stride) { int ck = i >> 3, o = i & 7;  wT2[i] = w2[o*288  + ck]; }
    for (int i = t0; i < 200*2;  i += stride) { int ck = i >> 1, o = i & 1;  wT3[i] = w3[o*200  + ck]; }
}

// ---------------------------------------------------------------------------
// Fused: edge-padded gradients -> orientation histogram soft-binning -> 4x4
// box pool (pad 2) => pooled (B,8,HP,WP). atan2 recomputed per window tap
// (16x redundancy, ~9M atan2 total — negligible) to avoid the 8-ch ang array.
__global__ void k_pool(const float* __restrict__ x, float* __restrict__ pooled) {
    int idx = blockIdx.x * blockDim.x + threadIdx.x;
    if (idx >= BB*NPOOL) return;
    int b = idx / NPOOL;
    int p = idx - b*NPOOL;
    int i = p / WP;
    int j = p - i*WP;
    const float* xb = x + b*NPIX;
    float a0=0.f,a1=0.f,a2=0.f,a3=0.f,a4=0.f,a5=0.f,a6=0.f,a7=0.f;
    #pragma unroll
    for (int di = 0; di < 4; ++di) {
        int hh = i + di - 2;
        if (hh < 0 || hh >= HH) continue;
        #pragma unroll
        for (int dj = 0; dj < 4; ++dj) {
            int ww = j + dj - 2;
            if (ww < 0 || ww >= WW) continue;
            float gx = xb[hh*WW + (ww+1 < WW ? ww+1 : WW-1)] - xb[hh*WW + (ww-1 >= 0 ? ww-1 : 0)];
            float gy = xb[(hh+1 < HH ? hh+1 : HH-1)*WW + ww] - xb[(hh-1 >= 0 ? hh-1 : 0)*WW + ww];
            float mag  = sqrtf(gx*gx + gy*gy + 1e-10f);
            float ori  = atan2f(gy, gx + 1e-10f) + TWO_PI;       // [pi, 3pi]
            float obig = ori * (8.0f / TWO_PI);                   // [4, 12]
            float b0f  = floorf(obig);
            float wo1  = obig - b0f;
            int ib0 = ((int)b0f) & 7;
            int ib1 = (ib0 + 1) & 7;
            float w0 = (1.0f - wo1) * mag;
            float w1v = wo1 * mag;
            a0 += (ib0==0) ? w0 : ((ib1==0) ? w1v : 0.f);
            a1 += (ib0==1) ? w0 : ((ib1==1) ? w1v : 0.f);
            a2 += (ib0==2) ? w0 : ((ib1==2) ? w1v : 0.f);
            a3 += (ib0==3) ? w0 : ((ib1==3) ? w1v : 0.f);
            a4 += (ib0==4) ? w0 : ((ib1==4) ? w1v : 0.f);
            a5 += (ib0==5) ? w0 : ((ib1==5) ? w1v : 0.f);
            a6 += (ib0==6) ? w0 : ((ib1==6) ? w1v : 0.f);
            a7 += (ib0==7) ? w0 : ((ib1==7) ? w1v : 0.f);
        }
    }
    float* pb = pooled + (size_t)b*8*NPOOL + p;
    const float s = 1.0f/16.0f;
    pb[0*NPOOL]=a0*s; pb[1*NPOOL]=a1*s; pb[2*NPOOL]=a2*s; pb[3*NPOOL]=a3*s;
    pb[4*NPOOL]=a4*s; pb[5*NPOOL]=a5*s; pb[6*NPOOL]=a6*s; pb[7*NPOOL]=a7*s;
}

// ---------------------------------------------------------------------------
// Per-pixel SIFT descriptor normalize. f[ch=c*16+i*4+j] gathers
// pooled[c, h+i-1, w+j-1] (zero OOB); l2norm -> clip 0.2 -> l2norm -> l1
// -> sqrt(v/l1 + 1e-10). 3 gather passes to stay register-light.
__global__ void k_feat(const float* __restrict__ pooled, bf16* __restrict__ f) {
    int idx = blockIdx.x * blockDim.x + threadIdx.x;
    if (idx >= BB*NPIX) return;
    int b = idx / NPIX;
    int p = idx - b*NPIX;
    int h = p / WW;
    int w = p - h*WW;
    const float* pb = pooled + (size_t)b*8*NPOOL;

    float s2 = 0.f;
    #pragma unroll
    for (int c = 0; c < 8; ++c)
        #pragma unroll
        for (int i = 0; i < 4; ++i) {
            int ph = h + i - 1;
            bool okh = (ph >= 0) && (ph < HP);
            #pragma unroll
            for (int j = 0; j < 4; ++j) {
                int pw = w + j - 1;
                float u = (okh && pw >= 0 && pw < WP) ? pb[c*NPOOL + ph*WP + pw] : 0.f;
                s2 += u*u;
            }
        }
    float inv1 = 1.0f / fmaxf(sqrtf(s2), 1e-12f);

    float sv2 = 0.f, sv1 = 0.f;
    #pragma unroll
    for (int c = 0; c < 8; ++c)
        #pragma unroll
        for (int i = 0; i < 4; ++i) {
            int ph = h + i - 1;
            bool okh = (ph >= 0) && (ph < HP);
            #pragma unroll
            for (int j = 0; j < 4; ++j) {
                int pw = w + j - 1;
                float u = (okh && pw >= 0 && pw < WP) ? pb[c*NPOOL + ph*WP + pw] : 0.f;
                float v = fminf(u*inv1, 0.2f);
                sv2 += v*v; sv1 += v;
            }
        }
    float inv2  = 1.0f / fmaxf(sqrtf(sv2), 1e-12f);
    float invl1 = 1.0f / fmaxf(sv1 * inv2, 1e-12f);

    bf16* fb = f + (size_t)b*128*NPIX + p;
    #pragma unroll
    for (int c = 0; c < 8; ++c)
        #pragma unroll
        for (int i = 0; i < 4; ++i) {
            int ph = h + i - 1;
            bool okh = (ph >= 0) && (ph < HP);
            #pragma unroll
            for (int j = 0; j < 4; ++j) {
                int pw = w + j - 1;
                float u = (okh && pw >= 0 && pw < WP) ? pb[c*NPOOL + ph*WP + pw] : 0.f;
                float v = fminf(u*inv1, 0.2f) * inv2;
                float fo = sqrtf(v*invl1 + 1e-10f);
                fb[(size_t)(c*16 + i*4 + j)*NPIX] = __float2bfloat16(fo);
            }
        }
}

// ---------------------------------------------------------------------------
// conv1: 128->32, 5x5, pad 2, ReLU. 16x16 tile, 8-ch LDS chunks, 32 f32 acc.
__global__ __launch_bounds__(256) void k_conv1(const bf16* __restrict__ f,
        const float* __restrict__ wT, const float* __restrict__ bias,
        float* __restrict__ out) {
    __shared__ float tile[8][20][20];
    int tx = threadIdx.x & 15, ty = threadIdx.x >> 4;
    int h0 = blockIdx.y * 16, w0 = blockIdx.x * 16, b = blockIdx.z;
    float acc[32];
    #pragma unroll
    for (int o = 0; o < 32; ++o) acc[o] = 0.f;

    for (int cc = 0; cc < 16; ++cc) {
        __syncthreads();
        for (int t = threadIdx.x; t < 8*400; t += 256) {
            int c = t / 400; int r = t - c*400; int lh = r / 20, lw = r - lh*20;
            int gh = h0 + lh - 2, gw = w0 + lw - 2;
            float v = 0.f;
            if (gh >= 0 && gh < HH && gw >= 0 && gw < WW)
                v = __bfloat162float(f[((size_t)(b*128 + cc*8 + c))*NPIX + gh*WW + gw]);
            tile[c][lh][lw] = v;
        }
        __syncthreads();
        for (int c = 0; c < 8; ++c) {
            for (int ky = 0; ky < 5; ++ky) {
                #pragma unroll
                for (int kx = 0; kx < 5; ++kx) {
                    float v = tile[c][ty+ky][tx+kx];
                    const float* wp = wT + (((cc*8+c)*25) + ky*5 + kx)*32;
                    #pragma unroll
                    for (int o = 0; o < 32; ++o) acc[o] = fmaf(v, wp[o], acc[o]);
                }
            }
        }
    }
    int h = h0 + ty, w = w0 + tx;
    if (h < HH) {
        float* op = out + (size_t)b*32*NPIX + h*WW + w;
        #pragma unroll
        for (int o = 0; o < 32; ++o) op[(size_t)o*NPIX] = fmaxf(acc[o] + bias[o], 0.f);
    }
}

// ---------------------------------------------------------------------------
// conv2: 32->8, 3x3, pad 1, ReLU.
__global__ __launch_bounds__(256) void k_conv2(const float* __restrict__ in,
        const float* __restrict__ wT, const float* __restrict__ bias,
        float* __restrict__ out) {
    __shared__ float tile[8][18][18];
    int tx = threadIdx.x & 15, ty = threadIdx.x >> 4;
    int h0 = blockIdx.y * 16, w0 = blockIdx.x * 16, b = blockIdx.z;
    float acc[8];
    #pragma unroll
    for (int o = 0; o < 8; ++o) acc[o] = 0.f;

    for (int cc = 0; cc < 4; ++cc) {
        __syncthreads();
        for (int t = threadIdx.x; t < 8*324; t += 256) {
            int c = t / 324; int r = t - c*324; int lh = r / 18, lw = r - lh*18;
            int gh = h0 + lh - 1, gw = w0 + lw - 1;
            float v = 0.f;
            if (gh >= 0 && gh < HH && gw >= 0 && gw < WW)
                v = in[((size_t)(b*32 + cc*8 + c))*NPIX + gh*WW + gw];
            tile[c][lh][lw] = v;
        }
        __syncthreads();
        for (int c = 0; c < 8; ++c) {
            #pragma unroll
            for (int ky = 0; ky < 3; ++ky) {
                #pragma unroll
                for (int kx = 0; kx < 3; ++kx) {
                    float v = tile[c][ty+ky][tx+kx];
                    const float* wp = wT + (((cc*8+c)*9) + ky*3 + kx)*8;
                    #pragma unroll
                    for (int o = 0; o < 8; ++o) acc[o] = fmaf(v, wp[o], acc[o]);
                }
            }
        }
    }
    int h = h0 + ty, w = w0 + tx;
    if (h < HH) {
        float* op = out + (size_t)b*8*NPIX + h*WW + w;
        #pragma unroll
        for (int o = 0; o < 8; ++o) op[(size_t)o*NPIX] = fmaxf(acc[o] + bias[o], 0.f);
    }
}

// ---------------------------------------------------------------------------
// conv3: 8->2, 5x5, pad 2, no activation.
__global__ __launch_bounds__(256) void k_conv3(const float* __restrict__ in,
        const float* __restrict__ wT, const float* __restrict__ bias,
        float* __restrict__ out) {
    __shared__ float tile[8][20][20];
    int tx = threadIdx.x & 15, ty = threadIdx.x >> 4;
    int h0 = blockIdx.y * 16, w0 = blockIdx.x * 16, b = blockIdx.z;
    float acc0 = 0.f, acc1 = 0.f;

    for (int t = threadIdx.x; t < 8*400; t += 256) {
        int c = t / 400; int r = t - c*400; int lh = r / 20, lw = r - lh*20;
        int gh = h0 + lh - 2, gw = w0 + lw - 2;
        float v = 0.f;
        if (gh >= 0 && gh < HH && gw >= 0 && gw < WW)
            v = in[((size_t)(b*8 + c))*NPIX + gh*WW + gw];
        tile[c][lh][lw] = v;
    }
    __syncthreads();
    for (int c = 0; c < 8; ++c) {
        for (int ky = 0; ky < 5; ++ky) {
            #pragma unroll
            for (int kx = 0; kx < 5; ++kx) {
                float v = tile[c][ty+ky][tx+kx];
                const float* wp = wT + ((c*25) + ky*5 + kx)*2;
                acc0 = fmaf(v, wp[0], acc0);
                acc1 = fmaf(v, wp[1], acc1);
            }
        }
    }
    int h = h0 + ty, w = w0 + tx;
    if (h < HH) {
        float* op = out + (size_t)b*2*NPIX + h*WW + w;
        op[0]    = acc0 + bias[0];
        op[NPIX] = acc1 + bias[1];
    }
}

// ---------------------------------------------------------------------------
__device__ __forceinline__ int refl(int i, int n) {
    if (i < 0) i = -i;
    if (i >= n) i = 2*n - 2 - i;
    return i;
}

// Joint bilateral blur, ksize=5, reflect pad. Guidance = [orig, orig], so
// cd = (2|d|)^2 = 4 d^2; exp(-0.5/0.01 * cd) = exp(-200 d^2).
__global__ void k_bilat(const float* __restrict__ c3, const float* __restrict__ x,
                        float* __restrict__ outb) {
    int idx = blockIdx.x * blockDim.x + threadIdx.x;
    if (idx >= BB*NPIX) return;
    int b = idx / NPIX;
    int p = idx - b*NPIX;
    int h = p / WW, w = p - h*WW;
    const float* xb = x + (size_t)b*NPIX;
    const float* f0 = c3 + (size_t)b*2*NPIX;
    const float* f1 = f0 + NPIX;

    float e1 = expf(-1.0f/4.5f), e2 = expf(-4.0f/4.5f);
    float sden = 1.0f + 2.f*e1 + 2.f*e2;
    float g1v[5] = { e2/sden, e1/sden, 1.0f/sden, e1/sden, e2/sden };

    float g = xb[p];
    float num0 = 0.f, num1 = 0.f, den = 0.f;
    #pragma unroll
    for (int dy = 0; dy < 5; ++dy) {
        int hh = refl(h + dy - 2, HH);
        #pragma unroll
        for (int dx = 0; dx < 5; ++dx) {
            int wc = refl(w + dx - 2, WW);
            float gs = xb[hh*WW + wc];
            float d = gs - g;
            float k = g1v[dy] * g1v[dx] * expf(-200.0f * d * d);
            num0 += f0[hh*WW + wc] * k;
            num1 += f1[hh*WW + wc] * k;
            den  += k;
        }
    }
    float invd = 1.0f / den;
    outb[(size_t)b*2*NPIX + p]        = num0 * invd;
    outb[(size_t)b*2*NPIX + NPIX + p] = num1 * invd;
}

// ---------------------------------------------------------------------------
__global__ void k_minmax1(const float* __restrict__ blur, float4* __restrict__ partial) {
    float umin = 3.0e38f, umax = -3.0e38f, vmin = 3.0e38f, vmax = -3.0e38f;
    for (int i = blockIdx.x*blockDim.x + threadIdx.x; i < BB*NPIX; i += gridDim.x*blockDim.x) {
        int b = i / NPIX; int p = i - b*NPIX;
        float u = blur[(size_t)b*2*NPIX + p];
        float v = blur[(size_t)b*2*NPIX + NPIX + p];
        umin = fminf(umin, u); umax = fmaxf(umax, u);
        vmin = fminf(vmin, v); vmax = fmaxf(vmax, v);
    }
    #pragma unroll
    for (int off = 32; off > 0; off >>= 1) {
        umin = fminf(umin, __shfl_down(umin, off));
        umax = fmaxf(umax, __shfl_down(umax, off));
        vmin = fminf(vmin, __shfl_down(vmin, off));
        vmax = fmaxf(vmax, __shfl_down(vmax, off));
    }
    __shared__ float4 sm[4];
    int lane = threadIdx.x & 63, wid = threadIdx.x >> 6;
    if (lane == 0) sm[wid] = make_float4(umin, umax, vmin, vmax);
    __syncthreads();
    if (threadIdx.x == 0) {
        float4 r = sm[0];
        for (int k = 1; k < 4; ++k) {
            r.x = fminf(r.x, sm[k].x); r.y = fmaxf(r.y, sm[k].y);
            r.z = fminf(r.z, sm[k].z); r.w = fmaxf(r.w, sm[k].w);
        }
        partial[blockIdx.x] = r;
    }
}

__global__ void k_minmax2(const float4* __restrict__ partial, float* __restrict__ sc) {
    float4 p = partial[threadIdx.x];   // 128 threads / 128 partials
    #pragma unroll
    for (int off = 32; off > 0; off >>= 1) {
        p.x = fminf(p.x, __shfl_down(p.x, off));
        p.y = fmaxf(p.y, __shfl_down(p.y, off));
        p.z = fminf(p.z, __shfl_down(p.z, off));
        p.w = fmaxf(p.w, __shfl_down(p.w, off));
    }
    __shared__ float4 sm[2];
    if ((threadIdx.x & 63) == 0) sm[threadIdx.x >> 6] = p;
    __syncthreads();
    if (threadIdx.x == 0) {
        sc[0] = fminf(sm[0].x, sm[1].x);
        sc[1] = fmaxf(sm[0].y, sm[1].y);
        sc[2] = fminf(sm[0].z, sm[1].z);
        sc[3] = fmaxf(sm[0].w, sm[1].w);
    }
}

__global__ void k_final(const float* __restrict__ blur, const float* __restrict__ x,
                        const float* __restrict__ sc, float* __restrict__ out) {
    int idx = blockIdx.x * blockDim.x + threadIdx.x;
    if (idx >= BB*NPIX) return;
    int b = idx / NPIX;
    int p = idx - b*NPIX;
    float umin = sc[0], umax = sc[1], vmin = sc[2], vmax = sc[3];
    float u = blur[(size_t)b*2*NPIX + p];
    float v = blur[(size_t)b*2*NPIX + NPIX + p];
    u = fminf(fmaxf((u - umin) / (umax - umin + 1e-6f), 0.f), 1.f) * 0.872f - 0.436f;
    v = fminf(fmaxf((v - vmin) / (vmax - vmin + 1e-6f), 0.f), 1.f) * 1.23f  - 0.615f;
    float y = x[(size_t)b*NPIX + p];
    out[(size_t)(b*3+0)*NPIX + p] = y + 1.14f*v;
    out[(size_t)(b*3+1)*NPIX + p] = y - 0.396f*u - 0.581f*v;
    out[(size_t)(b*3+2)*NPIX + p] = y + 2.029f*u;
}

// ---------------------------------------------------------------------------
extern "C" void kernel_launch(void* const* d_in, const int* in_sizes, int n_in,
                              void* d_out, int out_size, void* d_ws, size_t ws_size,
                              hipStream_t stream) {
    const float* x  = (const float*)d_in[0];
    const float* w1 = (const float*)d_in[1];
    const float* b1 = (const float*)d_in[2];
    const float* w2 = (const float*)d_in[3];
    const float* b2 = (const float*)d_in[4];
    const float* w3 = (const float*)d_in[5];
    const float* b3 = (const float*)d_in[6];
    float* out = (float*)d_out;
    char* ws = (char*)d_ws;

    // Workspace layout (bytes, 256-aligned). Region X is time-shared:
    //   [k_feat..k_conv1]  f (bf16, 141,557,760 B)
    //   [k_conv2..]        c2out @ X+0 (17,694,720 B)
    //   [k_conv3..]        c3out @ X+24,000,000 (4,423,680 B)
    //   [k_bilat..]        blur  @ X+32,000,000 (4,423,680 B)
    const size_t POOLED_OFF = 0;                      // 17,794,944
    const size_t X_OFF      = 17795072;
    const size_t Y_OFF      = X_OFF + 141557760;      // c1out f32: 70,778,880
    const size_t WT1_OFF    = Y_OFF + 70778880;       // 409,600
    const size_t WT2_OFF    = WT1_OFF + 409600;       // 9,216
    const size_t WT3_OFF    = WT2_OFF + 9216;         // 3,200
    const size_t PART_OFF   = WT3_OFF + 3328;         // 128 * 16
    const size_t SC_OFF     = PART_OFF + 2048;        // 16

    float*  pooled = (float*)(ws + POOLED_OFF);
    bf16*   f      = (bf16*) (ws + X_OFF);
    float*  c2o    = (float*)(ws + X_OFF);
    float*  c3o    = (float*)(ws + X_OFF + 24000000);
    float*  blur   = (float*)(ws + X_OFF + 32000000);
    float*  c1o    = (float*)(ws + Y_OFF);
    float*  wT1    = (float*)(ws + WT1_OFF);
    float*  wT2    = (float*)(ws + WT2_OFF);
    float*  wT3    = (float*)(ws + WT3_OFF);
    float4* part   = (float4*)(ws + PART_OFF);
    float*  sc     = (float*)(ws + SC_OFF);

    k_wprep<<<400, 256, 0, stream>>>(w1, w2, w3, wT1, wT2, wT3);
    k_pool<<<(BB*NPOOL + 255)/256, 256, 0, stream>>>(x, pooled);
    k_feat<<<(BB*NPIX + 255)/256, 256, 0, stream>>>(pooled, f);

    dim3 cg(WW/16, (HH + 15)/16, BB);   // 32 x 17 x 4
    k_conv1<<<cg, 256, 0, stream>>>(f, wT1, b1, c1o);
    k_conv2<<<cg, 256, 0, stream>>>(c1o, wT2, b2, c2o);
    k_conv3<<<cg, 256, 0, stream>>>(c2o, wT3, b3, c3o);

    k_bilat<<<(BB*NPIX + 255)/256, 256, 0, stream>>>(c3o, x, blur);
    k_minmax1<<<128, 256, 0, stream>>>(blur, part);
    k_minmax2<<<1, 128, 0, stream>>>(part, sc);
    k_final<<<(BB*NPIX + 255)/256, 256, 0, stream>>>(blur, x, sc, out);
}

// Round 2
// 1707.898 us; speedup vs baseline: 2.0700x; 2.0700x over previous
//
#include <hip/hip_runtime.h>
#include <hip/hip_bf16.h>

typedef __hip_bfloat16 bf16;
typedef __attribute__((ext_vector_type(8))) short short8v;
typedef __attribute__((ext_vector_type(4))) float f32x4;

#define HH 270
#define WW 512
#define BB 4
#define HP 271
#define WP 513
#define NPIX (HH*WW)      // 138240
#define NPOOL (HP*WP)     // 139023
#define TWO_PI 6.28318530717958647692f

// ---------------------------------------------------------------------------
// Weight prep:
//  - apack: conv1 weights pre-packed bf16 in MFMA A-fragment lane order:
//      [cc 4][tap 25][mtile 2][lane 64][j 8],  A[row=lane&15][k=(lane>>4)*8+j]
//      row = out-ch within m-tile, k = in-ch within 32-ch chunk.
//  - wT2 / wT3: f32 [CK][O] transposes for conv2/conv3 (unchanged kernels).
__global__ void k_wprep(const float* __restrict__ w1, const float* __restrict__ w2,
                        const float* __restrict__ w3, short* __restrict__ apack,
                        float* __restrict__ wT2, float* __restrict__ wT3) {
    int stride = gridDim.x * blockDim.x;
    int t0 = blockIdx.x * blockDim.x + threadIdx.x;
    for (int i = t0; i < 4*25*2*64*8; i += stride) {
        int idx = i;
        int j    = idx & 7;  idx >>= 3;
        int lane = idx & 63; idx >>= 6;
        int m    = idx & 1;  idx >>= 1;
        int t    = idx % 25;
        int cc   = idx / 25;
        int o = m*16 + (lane & 15);
        int c = cc*32 + (lane >> 4)*8 + j;
        float v = w1[o*3200 + c*25 + t];
        bf16 h = __float2bfloat16(v);
        apack[i] = *reinterpret_cast<short*>(&h);
    }
    for (int i = t0; i < 288*8;  i += stride) { int ck = i >> 3, o = i & 7;  wT2[i] = w2[o*288  + ck]; }
    for (int i = t0; i < 200*2;  i += stride) { int ck = i >> 1, o = i & 1;  wT3[i] = w3[o*200  + ck]; }
}

// ---------------------------------------------------------------------------
// Fused: edge-padded gradients -> orientation soft-binning -> 4x4 box pool.
__global__ void k_pool(const float* __restrict__ x, float* __restrict__ pooled) {
    int idx = blockIdx.x * blockDim.x + threadIdx.x;
    if (idx >= BB*NPOOL) return;
    int b = idx / NPOOL;
    int p = idx - b*NPOOL;
    int i = p / WP;
    int j = p - i*WP;
    const float* xb = x + b*NPIX;
    float a0=0.f,a1=0.f,a2=0.f,a3=0.f,a4=0.f,a5=0.f,a6=0.f,a7=0.f;
    #pragma unroll
    for (int di = 0; di < 4; ++di) {
        int hh = i + di - 2;
        if (hh < 0 || hh >= HH) continue;
        #pragma unroll
        for (int dj = 0; dj < 4; ++dj) {
            int ww = j + dj - 2;
            if (ww < 0 || ww >= WW) continue;
            float gx = xb[hh*WW + (ww+1 < WW ? ww+1 : WW-1)] - xb[hh*WW + (ww-1 >= 0 ? ww-1 : 0)];
            float gy = xb[(hh+1 < HH ? hh+1 : HH-1)*WW + ww] - xb[(hh-1 >= 0 ? hh-1 : 0)*WW + ww];
            float mag  = sqrtf(gx*gx + gy*gy + 1e-10f);
            float ori  = atan2f(gy, gx + 1e-10f) + TWO_PI;
            float obig = ori * (8.0f / TWO_PI);
            float b0f  = floorf(obig);
            float wo1  = obig - b0f;
            int ib0 = ((int)b0f) & 7;
            int ib1 = (ib0 + 1) & 7;
            float w0 = (1.0f - wo1) * mag;
            float w1v = wo1 * mag;
            a0 += (ib0==0) ? w0 : ((ib1==0) ? w1v : 0.f);
            a1 += (ib0==1) ? w0 : ((ib1==1) ? w1v : 0.f);
            a2 += (ib0==2) ? w0 : ((ib1==2) ? w1v : 0.f);
            a3 += (ib0==3) ? w0 : ((ib1==3) ? w1v : 0.f);
            a4 += (ib0==4) ? w0 : ((ib1==4) ? w1v : 0.f);
            a5 += (ib0==5) ? w0 : ((ib1==5) ? w1v : 0.f);
            a6 += (ib0==6) ? w0 : ((ib1==6) ? w1v : 0.f);
            a7 += (ib0==7) ? w0 : ((ib1==7) ? w1v : 0.f);
        }
    }
    float* pb = pooled + (size_t)b*8*NPOOL + p;
    const float s = 1.0f/16.0f;
    pb[0*NPOOL]=a0*s; pb[1*NPOOL]=a1*s; pb[2*NPOOL]=a2*s; pb[3*NPOOL]=a3*s;
    pb[4*NPOOL]=a4*s; pb[5*NPOOL]=a5*s; pb[6*NPOOL]=a6*s; pb[7*NPOOL]=a7*s;
}

// ---------------------------------------------------------------------------
// SIFT normalize. Output layout is now CHANNELS-LAST: f2[b][h][w][128] bf16,
// so conv1's LDS staging reads 64 B contiguous per (pixel, ch-chunk).
__global__ void k_feat(const float* __restrict__ pooled, short* __restrict__ f2) {
    int idx = blockIdx.x * blockDim.x + threadIdx.x;
    if (idx >= BB*NPIX) return;
    int b = idx / NPIX;
    int p = idx - b*NPIX;
    int h = p / WW;
    int w = p - h*WW;
    const float* pb = pooled + (size_t)b*8*NPOOL;

    float s2 = 0.f;
    #pragma unroll
    for (int c = 0; c < 8; ++c)
        #pragma unroll
        for (int i = 0; i < 4; ++i) {
            int ph = h + i - 1;
            bool okh = (ph >= 0) && (ph < HP);
            #pragma unroll
            for (int j = 0; j < 4; ++j) {
                int pw = w + j - 1;
                float u = (okh && pw >= 0 && pw < WP) ? pb[c*NPOOL + ph*WP + pw] : 0.f;
                s2 += u*u;
            }
        }
    float inv1 = 1.0f / fmaxf(sqrtf(s2), 1e-12f);

    float sv2 = 0.f, sv1 = 0.f;
    #pragma unroll
    for (int c = 0; c < 8; ++c)
        #pragma unroll
        for (int i = 0; i < 4; ++i) {
            int ph = h + i - 1;
            bool okh = (ph >= 0) && (ph < HP);
            #pragma unroll
            for (int j = 0; j < 4; ++j) {
                int pw = w + j - 1;
                float u = (okh && pw >= 0 && pw < WP) ? pb[c*NPOOL + ph*WP + pw] : 0.f;
                float v = fminf(u*inv1, 0.2f);
                sv2 += v*v; sv1 += v;
            }
        }
    float inv2  = 1.0f / fmaxf(sqrtf(sv2), 1e-12f);
    float invl1 = 1.0f / fmaxf(sv1 * inv2, 1e-12f);

    short* fb = f2 + ((size_t)b*NPIX + p)*128;
    #pragma unroll
    for (int c = 0; c < 8; ++c)
        #pragma unroll
        for (int i = 0; i < 4; ++i) {
            int ph = h + i - 1;
            bool okh = (ph >= 0) && (ph < HP);
            short4 pack;
            short* pk = (short*)&pack;
            #pragma unroll
            for (int j = 0; j < 4; ++j) {
                int pw = w + j - 1;
                float u = (okh && pw >= 0 && pw < WP) ? pb[c*NPOOL + ph*WP + pw] : 0.f;
                float v = fminf(u*inv1, 0.2f) * inv2;
                float fo = sqrtf(v*invl1 + 1e-10f);
                bf16 hb = __float2bfloat16(fo);
                pk[j] = *reinterpret_cast<short*>(&hb);
            }
            *reinterpret_cast<short4*>(fb + c*16 + i*4) = pack;
        }
}

// ---------------------------------------------------------------------------
// conv1 via MFMA implicit GEMM: 128->32 ch, 5x5, pad 2, ReLU.
// Block: 32 out x 128 px (one output row h, w-chunk of 128). 4 waves.
// Wave w: N-tiles {2w,2w+1} (16 px each) x M-tiles {0,1}. K = 4 ch-chunks x
// 25 taps x 32. LDS input tile [5 rows][132 px][40 ch] bf16 (pad 32->40 =>
// bank-balanced ds_read_b128 for B-fragments).
__global__ __launch_bounds__(256) void k_conv1(const short* __restrict__ f2,
        const short* __restrict__ apack, const float* __restrict__ bias,
        float* __restrict__ out) {
    __shared__ short S[5][132][40];   // 52,800 B
    const int tid  = threadIdx.x;
    const int lane = tid & 63;
    const int wid  = tid >> 6;
    const int h  = blockIdx.y;
    const int w0 = blockIdx.x * 128;
    const int b  = blockIdx.z;

    f32x4 acc00 = {0.f,0.f,0.f,0.f};  // m0, n-tile 2w
    f32x4 acc01 = {0.f,0.f,0.f,0.f};  // m0, n-tile 2w+1
    f32x4 acc10 = {0.f,0.f,0.f,0.f};  // m1, n-tile 2w
    f32x4 acc11 = {0.f,0.f,0.f,0.f};  // m1, n-tile 2w+1

    const int col   = lane & 15;      // pixel within n-tile / A row
    const int kgrp  = lane >> 4;      // k-group (8 k's each)
    const int pxb   = wid*32 + col;   // wave's first n-tile pixel base (in S px coords, before +kx)

    for (int cc = 0; cc < 4; ++cc) {
        __syncthreads();
        // stage: 5 rows x 132 px x 32 ch (64 B per (row,px), 4 x 16 B items)
        for (int i = tid; i < 5*132*4; i += 256) {
            int q  = i & 3;
            int r  = i >> 2;
            int px = r % 132;
            int ky = r / 132;
            int gh = h + ky - 2;
            int gw = w0 + px - 2;
            int4 v = {0,0,0,0};
            if (gh >= 0 && gh < HH && gw >= 0 && gw < WW)
                v = *reinterpret_cast<const int4*>(
                      f2 + (((size_t)b*HH + gh)*WW + gw)*128 + cc*32 + q*8);
            *reinterpret_cast<int4*>(&S[ky][px][q*8]) = v;
        }
        __syncthreads();

        for (int ky = 0; ky < 5; ++ky) {
            #pragma unroll
            for (int kx = 0; kx < 5; ++kx) {
                const short* ap = apack + ((size_t)(cc*25 + ky*5 + kx)*2)*512 + lane*8;
                short8v a0 = *reinterpret_cast<const short8v*>(ap);
                short8v a1 = *reinterpret_cast<const short8v*>(ap + 512);
                const short* bp = &S[ky][pxb + kx][kgrp*8];
                short8v b0 = *reinterpret_cast<const short8v*>(bp);
                short8v b1 = *reinterpret_cast<const short8v*>(bp + 16*40);
                acc00 = __builtin_amdgcn_mfma_f32_16x16x32_bf16(a0, b0, acc00, 0, 0, 0);
                acc10 = __builtin_amdgcn_mfma_f32_16x16x32_bf16(a1, b0, acc10, 0, 0, 0);
                acc01 = __builtin_amdgcn_mfma_f32_16x16x32_bf16(a0, b1, acc01, 0, 0, 0);
                acc11 = __builtin_amdgcn_mfma_f32_16x16x32_bf16(a1, b1, acc11, 0, 0, 0);
            }
        }
    }

    // Epilogue: D layout col=lane&15, row=(lane>>4)*4+r (m89-verified).
    const int row0 = kgrp*4;
    const int wpx0 = w0 + wid*32 + col;
    #pragma unroll
    for (int r = 0; r < 4; ++r) {
        int o0 = row0 + r;        // m-tile 0
        int o1 = 16 + row0 + r;   // m-tile 1
        float b0v = bias[o0], b1v = bias[o1];
        out[((size_t)b*32 + o0)*NPIX + h*WW + wpx0]      = fmaxf(acc00[r] + b0v, 0.f);
        out[((size_t)b*32 + o0)*NPIX + h*WW + wpx0 + 16] = fmaxf(acc01[r] + b0v, 0.f);
        out[((size_t)b*32 + o1)*NPIX + h*WW + wpx0]      = fmaxf(acc10[r] + b1v, 0.f);
        out[((size_t)b*32 + o1)*NPIX + h*WW + wpx0 + 16] = fmaxf(acc11[r] + b1v, 0.f);
    }
}

// ---------------------------------------------------------------------------
// conv2: 32->8, 3x3, pad 1, ReLU.
__global__ __launch_bounds__(256) void k_conv2(const float* __restrict__ in,
        const float* __restrict__ wT, const float* __restrict__ bias,
        float* __restrict__ out) {
    __shared__ float tile[8][18][18];
    int tx = threadIdx.x & 15, ty = threadIdx.x >> 4;
    int h0 = blockIdx.y * 16, w0 = blockIdx.x * 16, b = blockIdx.z;
    float acc[8];
    #pragma unroll
    for (int o = 0; o < 8; ++o) acc[o] = 0.f;

    for (int cc = 0; cc < 4; ++cc) {
        __syncthreads();
        for (int t = threadIdx.x; t < 8*324; t += 256) {
            int c = t / 324; int r = t - c*324; int lh = r / 18, lw = r - lh*18;
            int gh = h0 + lh - 1, gw = w0 + lw - 1;
            float v = 0.f;
            if (gh >= 0 && gh < HH && gw >= 0 && gw < WW)
                v = in[((size_t)(b*32 + cc*8 + c))*NPIX + gh*WW + gw];
            tile[c][lh][lw] = v;
        }
        __syncthreads();
        for (int c = 0; c < 8; ++c) {
            #pragma unroll
            for (int ky = 0; ky < 3; ++ky) {
                #pragma unroll
                for (int kx = 0; kx < 3; ++kx) {
                    float v = tile[c][ty+ky][tx+kx];
                    const float* wp = wT + (((cc*8+c)*9) + ky*3 + kx)*8;
                    #pragma unroll
                    for (int o = 0; o < 8; ++o) acc[o] = fmaf(v, wp[o], acc[o]);
                }
            }
        }
    }
    int h = h0 + ty, w = w0 + tx;
    if (h < HH) {
        float* op = out + (size_t)b*8*NPIX + h*WW + w;
        #pragma unroll
        for (int o = 0; o < 8; ++o) op[(size_t)o*NPIX] = fmaxf(acc[o] + bias[o], 0.f);
    }
}

// ---------------------------------------------------------------------------
// conv3: 8->2, 5x5, pad 2, no activation.
__global__ __launch_bounds__(256) void k_conv3(const float* __restrict__ in,
        const float* __restrict__ wT, const float* __restrict__ bias,
        float* __restrict__ out) {
    __shared__ float tile[8][20][20];
    int tx = threadIdx.x & 15, ty = threadIdx.x >> 4;
    int h0 = blockIdx.y * 16, w0 = blockIdx.x * 16, b = blockIdx.z;
    float acc0 = 0.f, acc1 = 0.f;

    for (int t = threadIdx.x; t < 8*400; t += 256) {
        int c = t / 400; int r = t - c*400; int lh = r / 20, lw = r - lh*20;
        int gh = h0 + lh - 2, gw = w0 + lw - 2;
        float v = 0.f;
        if (gh >= 0 && gh < HH && gw >= 0 && gw < WW)
            v = in[((size_t)(b*8 + c))*NPIX + gh*WW + gw];
        tile[c][lh][lw] = v;
    }
    __syncthreads();
    for (int c = 0; c < 8; ++c) {
        for (int ky = 0; ky < 5; ++ky) {
            #pragma unroll
            for (int kx = 0; kx < 5; ++kx) {
                float v = tile[c][ty+ky][tx+kx];
                const float* wp = wT + ((c*25) + ky*5 + kx)*2;
                acc0 = fmaf(v, wp[0], acc0);
                acc1 = fmaf(v, wp[1], acc1);
            }
        }
    }
    int h = h0 + ty, w = w0 + tx;
    if (h < HH) {
        float* op = out + (size_t)b*2*NPIX + h*WW + w;
        op[0]    = acc0 + bias[0];
        op[NPIX] = acc1 + bias[1];
    }
}

// ---------------------------------------------------------------------------
__device__ __forceinline__ int refl(int i, int n) {
    if (i < 0) i = -i;
    if (i >= n) i = 2*n - 2 - i;
    return i;
}

__global__ void k_bilat(const float* __restrict__ c3, const float* __restrict__ x,
                        float* __restrict__ outb) {
    int idx = blockIdx.x * blockDim.x + threadIdx.x;
    if (idx >= BB*NPIX) return;
    int b = idx / NPIX;
    int p = idx - b*NPIX;
    int h = p / WW, w = p - h*WW;
    const float* xb = x + (size_t)b*NPIX;
    const float* f0 = c3 + (size_t)b*2*NPIX;
    const float* f1 = f0 + NPIX;

    float e1 = expf(-1.0f/4.5f), e2 = expf(-4.0f/4.5f);
    float sden = 1.0f + 2.f*e1 + 2.f*e2;
    float g1v[5] = { e2/sden, e1/sden, 1.0f/sden, e1/sden, e2/sden };

    float g = xb[p];
    float num0 = 0.f, num1 = 0.f, den = 0.f;
    #pragma unroll
    for (int dy = 0; dy < 5; ++dy) {
        int hh = refl(h + dy - 2, HH);
        #pragma unroll
        for (int dx = 0; dx < 5; ++dx) {
            int wc = refl(w + dx - 2, WW);
            float gs = xb[hh*WW + wc];
            float d = gs - g;
            float k = g1v[dy] * g1v[dx] * expf(-200.0f * d * d);
            num0 += f0[hh*WW + wc] * k;
            num1 += f1[hh*WW + wc] * k;
            den  += k;
        }
    }
    float invd = 1.0f / den;
    outb[(size_t)b*2*NPIX + p]        = num0 * invd;
    outb[(size_t)b*2*NPIX + NPIX + p] = num1 * invd;
}

// ---------------------------------------------------------------------------
__global__ void k_minmax1(const float* __restrict__ blur, float4* __restrict__ partial) {
    float umin = 3.0e38f, umax = -3.0e38f, vmin = 3.0e38f, vmax = -3.0e38f;
    for (int i = blockIdx.x*blockDim.x + threadIdx.x; i < BB*NPIX; i += gridDim.x*blockDim.x) {
        int b = i / NPIX; int p = i - b*NPIX;
        float u = blur[(size_t)b*2*NPIX + p];
        float v = blur[(size_t)b*2*NPIX + NPIX + p];
        umin = fminf(umin, u); umax = fmaxf(umax, u);
        vmin = fminf(vmin, v); vmax = fmaxf(vmax, v);
    }
    #pragma unroll
    for (int off = 32; off > 0; off >>= 1) {
        umin = fminf(umin, __shfl_down(umin, off));
        umax = fmaxf(umax, __shfl_down(umax, off));
        vmin = fminf(vmin, __shfl_down(vmin, off));
        vmax = fmaxf(vmax, __shfl_down(vmax, off));
    }
    __shared__ float4 sm[4];
    int lane = threadIdx.x & 63, wid = threadIdx.x >> 6;
    if (lane == 0) sm[wid] = make_float4(umin, umax, vmin, vmax);
    __syncthreads();
    if (threadIdx.x == 0) {
        float4 r = sm[0];
        for (int k = 1; k < 4; ++k) {
            r.x = fminf(r.x, sm[k].x); r.y = fmaxf(r.y, sm[k].y);
            r.z = fminf(r.z, sm[k].z); r.w = fmaxf(r.w, sm[k].w);
        }
        partial[blockIdx.x] = r;
    }
}

__global__ void k_minmax2(const float4* __restrict__ partial, float* __restrict__ sc) {
    float4 p = partial[threadIdx.x];   // 128 threads / 128 partials
    #pragma unroll
    for (int off = 32; off > 0; off >>= 1) {
        p.x = fminf(p.x, __shfl_down(p.x, off));
        p.y = fmaxf(p.y, __shfl_down(p.y, off));
        p.z = fminf(p.z, __shfl_down(p.z, off));
        p.w = fmaxf(p.w, __shfl_down(p.w, off));
    }
    __shared__ float4 sm[2];
    if ((threadIdx.x & 63) == 0) sm[threadIdx.x >> 6] = p;
    __syncthreads();
    if (threadIdx.x == 0) {
        sc[0] = fminf(sm[0].x, sm[1].x);
        sc[1] = fmaxf(sm[0].y, sm[1].y);
        sc[2] = fminf(sm[0].z, sm[1].z);
        sc[3] = fmaxf(sm[0].w, sm[1].w);
    }
}

__global__ void k_final(const float* __restrict__ blur, const float* __restrict__ x,
                        const float* __restrict__ sc, float* __restrict__ out) {
    int idx = blockIdx.x * blockDim.x + threadIdx.x;
    if (idx >= BB*NPIX) return;
    int b = idx / NPIX;
    int p = idx - b*NPIX;
    float umin = sc[0], umax = sc[1], vmin = sc[2], vmax = sc[3];
    float u = blur[(size_t)b*2*NPIX + p];
    float v = blur[(size_t)b*2*NPIX + NPIX + p];
    u = fminf(fmaxf((u - umin) / (umax - umin + 1e-6f), 0.f), 1.f) * 0.872f - 0.436f;
    v = fminf(fmaxf((v - vmin) / (vmax - vmin + 1e-6f), 0.f), 1.f) * 1.23f  - 0.615f;
    float y = x[(size_t)b*NPIX + p];
    out[(size_t)(b*3+0)*NPIX + p] = y + 1.14f*v;
    out[(size_t)(b*3+1)*NPIX + p] = y - 0.396f*u - 0.581f*v;
    out[(size_t)(b*3+2)*NPIX + p] = y + 2.029f*u;
}

// ---------------------------------------------------------------------------
extern "C" void kernel_launch(void* const* d_in, const int* in_sizes, int n_in,
                              void* d_out, int out_size, void* d_ws, size_t ws_size,
                              hipStream_t stream) {
    const float* x  = (const float*)d_in[0];
    const float* w1 = (const float*)d_in[1];
    const float* b1 = (const float*)d_in[2];
    const float* w2 = (const float*)d_in[3];
    const float* b2 = (const float*)d_in[4];
    const float* w3 = (const float*)d_in[5];
    const float* b3 = (const float*)d_in[6];
    float* out = (float*)d_out;
    char* ws = (char*)d_ws;

    // Workspace layout (bytes). Region X time-shared:
    //   [k_feat..k_conv1]  f2 channels-last bf16 (141,557,760 B)
    //   [k_conv2..]        c2out @ X+0, c3out @ X+24e6, blur @ X+32e6
    const size_t POOLED_OFF = 0;                      // 17,794,944
    const size_t X_OFF      = 17795072;
    const size_t Y_OFF      = X_OFF + 141557760;      // c1out f32: 70,778,880
    const size_t AP_OFF     = Y_OFF + 70778880;       // apack bf16: 204,800
    const size_t WT2_OFF    = AP_OFF + 409600;        // 9,216
    const size_t WT3_OFF    = WT2_OFF + 9216;         // 3,200
    const size_t PART_OFF   = WT3_OFF + 3328;         // 128 * 16
    const size_t SC_OFF     = PART_OFF + 2048;        // 16

    float*  pooled = (float*)(ws + POOLED_OFF);
    short*  f2     = (short*)(ws + X_OFF);
    float*  c2o    = (float*)(ws + X_OFF);
    float*  c3o    = (float*)(ws + X_OFF + 24000000);
    float*  blur   = (float*)(ws + X_OFF + 32000000);
    float*  c1o    = (float*)(ws + Y_OFF);
    short*  apack  = (short*)(ws + AP_OFF);
    float*  wT2    = (float*)(ws + WT2_OFF);
    float*  wT3    = (float*)(ws + WT3_OFF);
    float4* part   = (float4*)(ws + PART_OFF);
    float*  sc     = (float*)(ws + SC_OFF);

    k_wprep<<<512, 256, 0, stream>>>(w1, w2, w3, apack, wT2, wT3);
    k_pool<<<(BB*NPOOL + 255)/256, 256, 0, stream>>>(x, pooled);
    k_feat<<<(BB*NPIX + 255)/256, 256, 0, stream>>>(pooled, f2);

    dim3 cg1(WW/128, HH, BB);           // 4 x 270 x 4
    k_conv1<<<cg1, 256, 0, stream>>>(f2, apack, b1, c1o);

    dim3 cg(WW/16, (HH + 15)/16, BB);   // 32 x 17 x 4
    k_conv2<<<cg, 256, 0, stream>>>(c1o, wT2, b2, c2o);
    k_conv3<<<cg, 256, 0, stream>>>(c2o, wT3, b3, c3o);

    k_bilat<<<(BB*NPIX + 255)/256, 256, 0, stream>>>(c3o, x, blur);
    k_minmax1<<<128, 256, 0, stream>>>(blur, part);
    k_minmax2<<<1, 128, 0, stream>>>(part, sc);
    k_final<<<(BB*NPIX + 255)/256, 256, 0, stream>>>(blur, x, sc, out);
}

// Round 3
// 478.393 us; speedup vs baseline: 7.3899x; 3.5701x over previous
//
#include <hip/hip_runtime.h>
#include <hip/hip_bf16.h>

typedef __hip_bfloat16 bf16;
typedef __attribute__((ext_vector_type(8))) short short8v;
typedef __attribute__((ext_vector_type(4))) float f32x4;

#define HH 270
#define WW 512
#define BB 4
#define HP 271
#define WP 513
#define NPIX (HH*WW)      // 138240
#define NPOOL (HP*WP)     // 139023
#define TWO_PI 6.28318530717958647692f

// ---------------------------------------------------------------------------
// Weight prep:
//  - apack: conv1 weights pre-packed bf16 in MFMA A-fragment lane order:
//      [cc 4][tap 25][mtile 2][lane 64][j 8],  A[row=lane&15][k=(lane>>4)*8+j]
//  - wT2 / wT3: f32 [CK][O] transposes for conv2/conv3.
__global__ void k_wprep(const float* __restrict__ w1, const float* __restrict__ w2,
                        const float* __restrict__ w3, short* __restrict__ apack,
                        float* __restrict__ wT2, float* __restrict__ wT3) {
    int stride = gridDim.x * blockDim.x;
    int t0 = blockIdx.x * blockDim.x + threadIdx.x;
    for (int i = t0; i < 4*25*2*64*8; i += stride) {
        int idx = i;
        int j    = idx & 7;  idx >>= 3;
        int lane = idx & 63; idx >>= 6;
        int m    = idx & 1;  idx >>= 1;
        int t    = idx % 25;
        int cc   = idx / 25;
        int o = m*16 + (lane & 15);
        int c = cc*32 + (lane >> 4)*8 + j;
        float v = w1[o*3200 + c*25 + t];
        bf16 h = __float2bfloat16(v);
        apack[i] = *reinterpret_cast<short*>(&h);
    }
    for (int i = t0; i < 288*8;  i += stride) { int ck = i >> 3, o = i & 7;  wT2[i] = w2[o*288  + ck]; }
    for (int i = t0; i < 200*2;  i += stride) { int ck = i >> 1, o = i & 1;  wT3[i] = w3[o*200  + ck]; }
}

// ---------------------------------------------------------------------------
// Fused: edge-padded gradients -> orientation soft-binning -> 4x4 box pool.
__global__ void k_pool(const float* __restrict__ x, float* __restrict__ pooled) {
    int idx = blockIdx.x * blockDim.x + threadIdx.x;
    if (idx >= BB*NPOOL) return;
    int b = idx / NPOOL;
    int p = idx - b*NPOOL;
    int i = p / WP;
    int j = p - i*WP;
    const float* xb = x + b*NPIX;
    float a0=0.f,a1=0.f,a2=0.f,a3=0.f,a4=0.f,a5=0.f,a6=0.f,a7=0.f;
    #pragma unroll
    for (int di = 0; di < 4; ++di) {
        int hh = i + di - 2;
        if (hh < 0 || hh >= HH) continue;
        #pragma unroll
        for (int dj = 0; dj < 4; ++dj) {
            int ww = j + dj - 2;
            if (ww < 0 || ww >= WW) continue;
            float gx = xb[hh*WW + (ww+1 < WW ? ww+1 : WW-1)] - xb[hh*WW + (ww-1 >= 0 ? ww-1 : 0)];
            float gy = xb[(hh+1 < HH ? hh+1 : HH-1)*WW + ww] - xb[(hh-1 >= 0 ? hh-1 : 0)*WW + ww];
            float mag  = sqrtf(gx*gx + gy*gy + 1e-10f);
            float ori  = atan2f(gy, gx + 1e-10f) + TWO_PI;
            float obig = ori * (8.0f / TWO_PI);
            float b0f  = floorf(obig);
            float wo1  = obig - b0f;
            int ib0 = ((int)b0f) & 7;
            int ib1 = (ib0 + 1) & 7;
            float w0 = (1.0f - wo1) * mag;
            float w1v = wo1 * mag;
            a0 += (ib0==0) ? w0 : ((ib1==0) ? w1v : 0.f);
            a1 += (ib0==1) ? w0 : ((ib1==1) ? w1v : 0.f);
            a2 += (ib0==2) ? w0 : ((ib1==2) ? w1v : 0.f);
            a3 += (ib0==3) ? w0 : ((ib1==3) ? w1v : 0.f);
            a4 += (ib0==4) ? w0 : ((ib1==4) ? w1v : 0.f);
            a5 += (ib0==5) ? w0 : ((ib1==5) ? w1v : 0.f);
            a6 += (ib0==6) ? w0 : ((ib1==6) ? w1v : 0.f);
            a7 += (ib0==7) ? w0 : ((ib1==7) ? w1v : 0.f);
        }
    }
    float* pb = pooled + (size_t)b*8*NPOOL + p;
    const float s = 1.0f/16.0f;
    pb[0*NPOOL]=a0*s; pb[1*NPOOL]=a1*s; pb[2*NPOOL]=a2*s; pb[3*NPOOL]=a3*s;
    pb[4*NPOOL]=a4*s; pb[5*NPOOL]=a5*s; pb[6*NPOOL]=a6*s; pb[7*NPOOL]=a7*s;
}

// ---------------------------------------------------------------------------
// SIFT normalize, tiled. 16x16 px block stages pooled[8][19][19] in LDS
// (reads: 854 MB global -> ~25 MB). Final values packed in 64 VGPRs (static
// indices), burst-written as 16 consecutive dwordx4 per pixel (kills the
// 15x partial-line write amplification seen in R2 counters).
__global__ __launch_bounds__(256) void k_feat(const float* __restrict__ pooled,
                                              short* __restrict__ f2) {
    __shared__ float T[8][19][19];
    const int tx = threadIdx.x & 15, ty = threadIdx.x >> 4;
    const int w0 = blockIdx.x * 16, h0 = blockIdx.y * 16, b = blockIdx.z;
    const float* pb = pooled + (size_t)b*8*NPOOL;

    for (int i = threadIdx.x; i < 8*361; i += 256) {
        int c = i / 361; int r = i - c*361; int lh = r / 19, lw = r - lh*19;
        int ph = h0 + lh - 1, pw = w0 + lw - 1;
        float v = 0.f;
        if (ph >= 0 && ph < HP && pw >= 0 && pw < WP)
            v = pb[c*NPOOL + ph*WP + pw];
        T[c][lh][lw] = v;
    }
    __syncthreads();

    float s2 = 0.f;
    #pragma unroll
    for (int c = 0; c < 8; ++c)
        #pragma unroll
        for (int i = 0; i < 4; ++i)
            #pragma unroll
            for (int j = 0; j < 4; ++j) {
                float u = T[c][ty+i][tx+j];
                s2 += u*u;
            }
    float inv1 = 1.0f / fmaxf(sqrtf(s2), 1e-12f);

    float sv2 = 0.f, sv1 = 0.f;
    #pragma unroll
    for (int c = 0; c < 8; ++c)
        #pragma unroll
        for (int i = 0; i < 4; ++i)
            #pragma unroll
            for (int j = 0; j < 4; ++j) {
                float u = T[c][ty+i][tx+j];
                float v = fminf(u*inv1, 0.2f);
                sv2 += v*v; sv1 += v;
            }
    float inv2  = 1.0f / fmaxf(sqrtf(sv2), 1e-12f);
    float invl1 = 1.0f / fmaxf(sv1 * inv2, 1e-12f);

    int outv[64];
    #pragma unroll
    for (int c = 0; c < 8; ++c)
        #pragma unroll
        for (int i = 0; i < 4; ++i)
            #pragma unroll
            for (int jj = 0; jj < 2; ++jj) {
                float u0 = T[c][ty+i][tx+jj*2];
                float u1 = T[c][ty+i][tx+jj*2+1];
                float v0 = fminf(u0*inv1, 0.2f) * inv2;
                float v1 = fminf(u1*inv1, 0.2f) * inv2;
                float fo0 = sqrtf(v0*invl1 + 1e-10f);
                float fo1 = sqrtf(v1*invl1 + 1e-10f);
                bf16 hb0 = __float2bfloat16(fo0);
                bf16 hb1 = __float2bfloat16(fo1);
                unsigned lo = *reinterpret_cast<unsigned short*>(&hb0);
                unsigned hi = *reinterpret_cast<unsigned short*>(&hb1);
                outv[c*8 + i*2 + jj] = (int)(lo | (hi << 16));
            }

    int h = h0 + ty, w = w0 + tx;
    if (h < HH) {
        int4* fb = reinterpret_cast<int4*>(f2 + ((size_t)b*NPIX + h*WW + w)*128);
        #pragma unroll
        for (int q = 0; q < 16; ++q) {
            int4 v4;
            v4.x = outv[q*4]; v4.y = outv[q*4+1]; v4.z = outv[q*4+2]; v4.w = outv[q*4+3];
            fb[q] = v4;
        }
    }
}

// ---------------------------------------------------------------------------
// conv1 via MFMA implicit GEMM: 128->32 ch, 5x5, pad 2, ReLU.
__global__ __launch_bounds__(256) void k_conv1(const short* __restrict__ f2,
        const short* __restrict__ apack, const float* __restrict__ bias,
        float* __restrict__ out) {
    __shared__ short S[5][132][40];   // 52,800 B
    const int tid  = threadIdx.x;
    const int lane = tid & 63;
    const int wid  = tid >> 6;
    const int h  = blockIdx.y;
    const int w0 = blockIdx.x * 128;
    const int b  = blockIdx.z;

    f32x4 acc00 = {0.f,0.f,0.f,0.f};
    f32x4 acc01 = {0.f,0.f,0.f,0.f};
    f32x4 acc10 = {0.f,0.f,0.f,0.f};
    f32x4 acc11 = {0.f,0.f,0.f,0.f};

    const int col   = lane & 15;
    const int kgrp  = lane >> 4;
    const int pxb   = wid*32 + col;

    for (int cc = 0; cc < 4; ++cc) {
        __syncthreads();
        for (int i = tid; i < 5*132*4; i += 256) {
            int q  = i & 3;
            int r  = i >> 2;
            int px = r % 132;
            int ky = r / 132;
            int gh = h + ky - 2;
            int gw = w0 + px - 2;
            int4 v = {0,0,0,0};
            if (gh >= 0 && gh < HH && gw >= 0 && gw < WW)
                v = *reinterpret_cast<const int4*>(
                      f2 + (((size_t)b*HH + gh)*WW + gw)*128 + cc*32 + q*8);
            *reinterpret_cast<int4*>(&S[ky][px][q*8]) = v;
        }
        __syncthreads();

        for (int ky = 0; ky < 5; ++ky) {
            #pragma unroll
            for (int kx = 0; kx < 5; ++kx) {
                const short* ap = apack + ((size_t)(cc*25 + ky*5 + kx)*2)*512 + lane*8;
                short8v a0 = *reinterpret_cast<const short8v*>(ap);
                short8v a1 = *reinterpret_cast<const short8v*>(ap + 512);
                const short* bp = &S[ky][pxb + kx][kgrp*8];
                short8v b0 = *reinterpret_cast<const short8v*>(bp);
                short8v b1 = *reinterpret_cast<const short8v*>(bp + 16*40);
                acc00 = __builtin_amdgcn_mfma_f32_16x16x32_bf16(a0, b0, acc00, 0, 0, 0);
                acc10 = __builtin_amdgcn_mfma_f32_16x16x32_bf16(a1, b0, acc10, 0, 0, 0);
                acc01 = __builtin_amdgcn_mfma_f32_16x16x32_bf16(a0, b1, acc01, 0, 0, 0);
                acc11 = __builtin_amdgcn_mfma_f32_16x16x32_bf16(a1, b1, acc11, 0, 0, 0);
            }
        }
    }

    const int row0 = kgrp*4;
    const int wpx0 = w0 + wid*32 + col;
    #pragma unroll
    for (int r = 0; r < 4; ++r) {
        int o0 = row0 + r;
        int o1 = 16 + row0 + r;
        float b0v = bias[o0], b1v = bias[o1];
        out[((size_t)b*32 + o0)*NPIX + h*WW + wpx0]      = fmaxf(acc00[r] + b0v, 0.f);
        out[((size_t)b*32 + o0)*NPIX + h*WW + wpx0 + 16] = fmaxf(acc01[r] + b0v, 0.f);
        out[((size_t)b*32 + o1)*NPIX + h*WW + wpx0]      = fmaxf(acc10[r] + b1v, 0.f);
        out[((size_t)b*32 + o1)*NPIX + h*WW + wpx0 + 16] = fmaxf(acc11[r] + b1v, 0.f);
    }
}

// ---------------------------------------------------------------------------
// conv2: 32->8, 3x3, pad 1, ReLU.
__global__ __launch_bounds__(256) void k_conv2(const float* __restrict__ in,
        const float* __restrict__ wT, const float* __restrict__ bias,
        float* __restrict__ out) {
    __shared__ float tile[8][18][18];
    int tx = threadIdx.x & 15, ty = threadIdx.x >> 4;
    int h0 = blockIdx.y * 16, w0 = blockIdx.x * 16, b = blockIdx.z;
    float acc[8];
    #pragma unroll
    for (int o = 0; o < 8; ++o) acc[o] = 0.f;

    for (int cc = 0; cc < 4; ++cc) {
        __syncthreads();
        for (int t = threadIdx.x; t < 8*324; t += 256) {
            int c = t / 324; int r = t - c*324; int lh = r / 18, lw = r - lh*18;
            int gh = h0 + lh - 1, gw = w0 + lw - 1;
            float v = 0.f;
            if (gh >= 0 && gh < HH && gw >= 0 && gw < WW)
                v = in[((size_t)(b*32 + cc*8 + c))*NPIX + gh*WW + gw];
            tile[c][lh][lw] = v;
        }
        __syncthreads();
        for (int c = 0; c < 8; ++c) {
            #pragma unroll
            for (int ky = 0; ky < 3; ++ky) {
                #pragma unroll
                for (int kx = 0; kx < 3; ++kx) {
                    float v = tile[c][ty+ky][tx+kx];
                    const float* wp = wT + (((cc*8+c)*9) + ky*3 + kx)*8;
                    #pragma unroll
                    for (int o = 0; o < 8; ++o) acc[o] = fmaf(v, wp[o], acc[o]);
                }
            }
        }
    }
    int h = h0 + ty, w = w0 + tx;
    if (h < HH) {
        float* op = out + (size_t)b*8*NPIX + h*WW + w;
        #pragma unroll
        for (int o = 0; o < 8; ++o) op[(size_t)o*NPIX] = fmaxf(acc[o] + bias[o], 0.f);
    }
}

// ---------------------------------------------------------------------------
// conv3: 8->2, 5x5, pad 2, no activation.
__global__ __launch_bounds__(256) void k_conv3(const float* __restrict__ in,
        const float* __restrict__ wT, const float* __restrict__ bias,
        float* __restrict__ out) {
    __shared__ float tile[8][20][20];
    int tx = threadIdx.x & 15, ty = threadIdx.x >> 4;
    int h0 = blockIdx.y * 16, w0 = blockIdx.x * 16, b = blockIdx.z;
    float acc0 = 0.f, acc1 = 0.f;

    for (int t = threadIdx.x; t < 8*400; t += 256) {
        int c = t / 400; int r = t - c*400; int lh = r / 20, lw = r - lh*20;
        int gh = h0 + lh - 2, gw = w0 + lw - 2;
        float v = 0.f;
        if (gh >= 0 && gh < HH && gw >= 0 && gw < WW)
            v = in[((size_t)(b*8 + c))*NPIX + gh*WW + gw];
        tile[c][lh][lw] = v;
    }
    __syncthreads();
    for (int c = 0; c < 8; ++c) {
        for (int ky = 0; ky < 5; ++ky) {
            #pragma unroll
            for (int kx = 0; kx < 5; ++kx) {
                float v = tile[c][ty+ky][tx+kx];
                const float* wp = wT + ((c*25) + ky*5 + kx)*2;
                acc0 = fmaf(v, wp[0], acc0);
                acc1 = fmaf(v, wp[1], acc1);
            }
        }
    }
    int h = h0 + ty, w = w0 + tx;
    if (h < HH) {
        float* op = out + (size_t)b*2*NPIX + h*WW + w;
        op[0]    = acc0 + bias[0];
        op[NPIX] = acc1 + bias[1];
    }
}

// ---------------------------------------------------------------------------
__device__ __forceinline__ int refl(int i, int n) {
    if (i < 0) i = -i;
    if (i >= n) i = 2*n - 2 - i;
    return i;
}

__global__ void k_bilat(const float* __restrict__ c3, const float* __restrict__ x,
                        float* __restrict__ outb) {
    int idx = blockIdx.x * blockDim.x + threadIdx.x;
    if (idx >= BB*NPIX) return;
    int b = idx / NPIX;
    int p = idx - b*NPIX;
    int h = p / WW, w = p - h*WW;
    const float* xb = x + (size_t)b*NPIX;
    const float* f0 = c3 + (size_t)b*2*NPIX;
    const float* f1 = f0 + NPIX;

    float e1 = expf(-1.0f/4.5f), e2 = expf(-4.0f/4.5f);
    float sden = 1.0f + 2.f*e1 + 2.f*e2;
    float g1v[5] = { e2/sden, e1/sden, 1.0f/sden, e1/sden, e2/sden };

    float g = xb[p];
    float num0 = 0.f, num1 = 0.f, den = 0.f;
    #pragma unroll
    for (int dy = 0; dy < 5; ++dy) {
        int hh = refl(h + dy - 2, HH);
        #pragma unroll
        for (int dx = 0; dx < 5; ++dx) {
            int wc = refl(w + dx - 2, WW);
            float gs = xb[hh*WW + wc];
            float d = gs - g;
            float k = g1v[dy] * g1v[dx] * expf(-200.0f * d * d);
            num0 += f0[hh*WW + wc] * k;
            num1 += f1[hh*WW + wc] * k;
            den  += k;
        }
    }
    float invd = 1.0f / den;
    outb[(size_t)b*2*NPIX + p]        = num0 * invd;
    outb[(size_t)b*2*NPIX + NPIX + p] = num1 * invd;
}

// ---------------------------------------------------------------------------
__global__ void k_minmax1(const float* __restrict__ blur, float4* __restrict__ partial) {
    float umin = 3.0e38f, umax = -3.0e38f, vmin = 3.0e38f, vmax = -3.0e38f;
    for (int i = blockIdx.x*blockDim.x + threadIdx.x; i < BB*NPIX; i += gridDim.x*blockDim.x) {
        int b = i / NPIX; int p = i - b*NPIX;
        float u = blur[(size_t)b*2*NPIX + p];
        float v = blur[(size_t)b*2*NPIX + NPIX + p];
        umin = fminf(umin, u); umax = fmaxf(umax, u);
        vmin = fminf(vmin, v); vmax = fmaxf(vmax, v);
    }
    #pragma unroll
    for (int off = 32; off > 0; off >>= 1) {
        umin = fminf(umin, __shfl_down(umin, off));
        umax = fmaxf(umax, __shfl_down(umax, off));
        vmin = fminf(vmin, __shfl_down(vmin, off));
        vmax = fmaxf(vmax, __shfl_down(vmax, off));
    }
    __shared__ float4 sm[4];
    int lane = threadIdx.x & 63, wid = threadIdx.x >> 6;
    if (lane == 0) sm[wid] = make_float4(umin, umax, vmin, vmax);
    __syncthreads();
    if (threadIdx.x == 0) {
        float4 r = sm[0];
        for (int k = 1; k < 4; ++k) {
            r.x = fminf(r.x, sm[k].x); r.y = fmaxf(r.y, sm[k].y);
            r.z = fminf(r.z, sm[k].z); r.w = fmaxf(r.w, sm[k].w);
        }
        partial[blockIdx.x] = r;
    }
}

__global__ void k_minmax2(const float4* __restrict__ partial, float* __restrict__ sc) {
    float4 p = partial[threadIdx.x];
    #pragma unroll
    for (int off = 32; off > 0; off >>= 1) {
        p.x = fminf(p.x, __shfl_down(p.x, off));
        p.y = fmaxf(p.y, __shfl_down(p.y, off));
        p.z = fminf(p.z, __shfl_down(p.z, off));
        p.w = fmaxf(p.w, __shfl_down(p.w, off));
    }
    __shared__ float4 sm[2];
    if ((threadIdx.x & 63) == 0) sm[threadIdx.x >> 6] = p;
    __syncthreads();
    if (threadIdx.x == 0) {
        sc[0] = fminf(sm[0].x, sm[1].x);
        sc[1] = fmaxf(sm[0].y, sm[1].y);
        sc[2] = fminf(sm[0].z, sm[1].z);
        sc[3] = fmaxf(sm[0].w, sm[1].w);
    }
}

__global__ void k_final(const float* __restrict__ blur, const float* __restrict__ x,
                        const float* __restrict__ sc, float* __restrict__ out) {
    int idx = blockIdx.x * blockDim.x + threadIdx.x;
    if (idx >= BB*NPIX) return;
    int b = idx / NPIX;
    int p = idx - b*NPIX;
    float umin = sc[0], umax = sc[1], vmin = sc[2], vmax = sc[3];
    float u = blur[(size_t)b*2*NPIX + p];
    float v = blur[(size_t)b*2*NPIX + NPIX + p];
    u = fminf(fmaxf((u - umin) / (umax - umin + 1e-6f), 0.f), 1.f) * 0.872f - 0.436f;
    v = fminf(fmaxf((v - vmin) / (vmax - vmin + 1e-6f), 0.f), 1.f) * 1.23f  - 0.615f;
    float y = x[(size_t)b*NPIX + p];
    out[(size_t)(b*3+0)*NPIX + p] = y + 1.14f*v;
    out[(size_t)(b*3+1)*NPIX + p] = y - 0.396f*u - 0.581f*v;
    out[(size_t)(b*3+2)*NPIX + p] = y + 2.029f*u;
}

// ---------------------------------------------------------------------------
extern "C" void kernel_launch(void* const* d_in, const int* in_sizes, int n_in,
                              void* d_out, int out_size, void* d_ws, size_t ws_size,
                              hipStream_t stream) {
    const float* x  = (const float*)d_in[0];
    const float* w1 = (const float*)d_in[1];
    const float* b1 = (const float*)d_in[2];
    const float* w2 = (const float*)d_in[3];
    const float* b2 = (const float*)d_in[4];
    const float* w3 = (const float*)d_in[5];
    const float* b3 = (const float*)d_in[6];
    float* out = (float*)d_out;
    char* ws = (char*)d_ws;

    const size_t POOLED_OFF = 0;                      // 17,794,944
    const size_t X_OFF      = 17795072;
    const size_t Y_OFF      = X_OFF + 141557760;      // c1out f32: 70,778,880
    const size_t AP_OFF     = Y_OFF + 70778880;       // apack bf16: 204,800
    const size_t WT2_OFF    = AP_OFF + 409600;        // 9,216
    const size_t WT3_OFF    = WT2_OFF + 9216;         // 3,200
    const size_t PART_OFF   = WT3_OFF + 3328;         // 128 * 16
    const size_t SC_OFF     = PART_OFF + 2048;        // 16

    float*  pooled = (float*)(ws + POOLED_OFF);
    short*  f2     = (short*)(ws + X_OFF);
    float*  c2o    = (float*)(ws + X_OFF);
    float*  c3o    = (float*)(ws + X_OFF + 24000000);
    float*  blur   = (float*)(ws + X_OFF + 32000000);
    float*  c1o    = (float*)(ws + Y_OFF);
    short*  apack  = (short*)(ws + AP_OFF);
    float*  wT2    = (float*)(ws + WT2_OFF);
    float*  wT3    = (float*)(ws + WT3_OFF);
    float4* part   = (float4*)(ws + PART_OFF);
    float*  sc     = (float*)(ws + SC_OFF);

    k_wprep<<<512, 256, 0, stream>>>(w1, w2, w3, apack, wT2, wT3);
    k_pool<<<(BB*NPOOL + 255)/256, 256, 0, stream>>>(x, pooled);

    dim3 fg(WW/16, (HH + 15)/16, BB);   // 32 x 17 x 4
    k_feat<<<fg, 256, 0, stream>>>(pooled, f2);

    dim3 cg1(WW/128, HH, BB);           // 4 x 270 x 4
    k_conv1<<<cg1, 256, 0, stream>>>(f2, apack, b1, c1o);

    dim3 cg(WW/16, (HH + 15)/16, BB);   // 32 x 17 x 4
    k_conv2<<<cg, 256, 0, stream>>>(c1o, wT2, b2, c2o);
    k_conv3<<<cg, 256, 0, stream>>>(c2o, wT3, b3, c3o);

    k_bilat<<<(BB*NPIX + 255)/256, 256, 0, stream>>>(c3o, x, blur);
    k_minmax1<<<128, 256, 0, stream>>>(blur, part);
    k_minmax2<<<1, 128, 0, stream>>>(part, sc);
    k_final<<<(BB*NPIX + 255)/256, 256, 0, stream>>>(blur, x, sc, out);
}

// Round 4
// 455.606 us; speedup vs baseline: 7.7595x; 1.0500x over previous
//
#include <hip/hip_runtime.h>
#include <hip/hip_bf16.h>

typedef __hip_bfloat16 bf16;
typedef __attribute__((ext_vector_type(8))) short short8v;
typedef __attribute__((ext_vector_type(4))) float f32x4;
typedef __attribute__((ext_vector_type(16))) float f32x16;

#define HH 270
#define WW 512
#define BB 4
#define HP 271
#define WP 513
#define NPIX (HH*WW)      // 138240
#define NPOOL (HP*WP)     // 139023
#define TWO_PI 6.28318530717958647692f

// ---------------------------------------------------------------------------
// Weight prep:
//  - apack: conv1 weights pre-packed bf16 for mfma_f32_32x32x16_bf16 A-frag:
//      [cc 4][tap 25][kh 2][lane 64][j 8]
//      A[row = lane&31][k = (lane>>5)*8 + j], in-ch = cc*32 + kh*16 + k
//  - wT2 / wT3: f32 [CK][O] transposes for conv2/conv3.
__global__ void k_wprep(const float* __restrict__ w1, const float* __restrict__ w2,
                        const float* __restrict__ w3, short* __restrict__ apack,
                        float* __restrict__ wT2, float* __restrict__ wT3) {
    int stride = gridDim.x * blockDim.x;
    int t0 = blockIdx.x * blockDim.x + threadIdx.x;
    for (int i = t0; i < 4*25*2*64*8; i += stride) {
        int idx = i;
        int j    = idx & 7;  idx >>= 3;
        int lane = idx & 63; idx >>= 6;
        int kh   = idx & 1;  idx >>= 1;
        int t    = idx % 25;
        int cc   = idx / 25;
        int o = lane & 31;
        int c = cc*32 + kh*16 + (lane >> 5)*8 + j;
        float v = w1[o*3200 + c*25 + t];
        bf16 h = __float2bfloat16(v);
        apack[i] = *reinterpret_cast<short*>(&h);
    }
    for (int i = t0; i < 288*8;  i += stride) { int ck = i >> 3, o = i & 7;  wT2[i] = w2[o*288  + ck]; }
    for (int i = t0; i < 200*2;  i += stride) { int ck = i >> 1, o = i & 1;  wT3[i] = w3[o*200  + ck]; }
}

// ---------------------------------------------------------------------------
// Tiled pool: 16x16 output tile. Per-pixel grad/atan2/soft-bin computed ONCE
// into an 8-ch LDS histogram (19x19 region), then each thread 4x4-window-sums
// its 8 channels. (Old version recomputed atan2 16x per pixel.)
__global__ __launch_bounds__(256) void k_pool(const float* __restrict__ x,
                                              float* __restrict__ pooled) {
    __shared__ float hist[8][19][20];
    const int tx = threadIdx.x & 15, ty = threadIdx.x >> 4;
    const int j0 = blockIdx.x * 16, i0 = blockIdx.y * 16, b = blockIdx.z;
    const float* xb = x + (size_t)b * NPIX;

    for (int i = threadIdx.x; i < 8*19*20; i += 256) ((float*)hist)[i] = 0.f;
    __syncthreads();

    for (int i = threadIdx.x; i < 361; i += 256) {
        int lh = i / 19, lw = i - lh*19;
        int hh = i0 + lh - 2, ww = j0 + lw - 2;
        if (hh >= 0 && hh < HH && ww >= 0 && ww < WW) {
            float gx = xb[hh*WW + (ww+1 < WW ? ww+1 : WW-1)] - xb[hh*WW + (ww-1 >= 0 ? ww-1 : 0)];
            float gy = xb[(hh+1 < HH ? hh+1 : HH-1)*WW + ww] - xb[(hh-1 >= 0 ? hh-1 : 0)*WW + ww];
            float mag  = sqrtf(gx*gx + gy*gy + 1e-10f);
            float ori  = atan2f(gy, gx + 1e-10f) + TWO_PI;
            float obig = ori * (8.0f / TWO_PI);
            float b0f  = floorf(obig);
            float wo1  = obig - b0f;
            int ib0 = ((int)b0f) & 7;
            int ib1 = (ib0 + 1) & 7;
            hist[ib0][lh][lw] += (1.0f - wo1) * mag;
            hist[ib1][lh][lw] += wo1 * mag;
        }
    }
    __syncthreads();

    int i = i0 + ty, j = j0 + tx;
    if (i < HP && j < WP) {
        float a[8];
        #pragma unroll
        for (int c = 0; c < 8; ++c) a[c] = 0.f;
        #pragma unroll
        for (int di = 0; di < 4; ++di)
            #pragma unroll
            for (int dj = 0; dj < 4; ++dj) {
                #pragma unroll
                for (int c = 0; c < 8; ++c)
                    a[c] += hist[c][ty+di][tx+dj];
            }
        float* pb = pooled + (size_t)b*8*NPOOL + i*WP + j;
        const float s = 1.0f/16.0f;
        #pragma unroll
        for (int c = 0; c < 8; ++c) pb[c*NPOOL] = a[c]*s;
    }
}

// ---------------------------------------------------------------------------
// SIFT normalize, tiled; channels-last bf16 output, burst dwordx4 writes.
__global__ __launch_bounds__(256) void k_feat(const float* __restrict__ pooled,
                                              short* __restrict__ f2) {
    __shared__ float T[8][19][19];
    const int tx = threadIdx.x & 15, ty = threadIdx.x >> 4;
    const int w0 = blockIdx.x * 16, h0 = blockIdx.y * 16, b = blockIdx.z;
    const float* pb = pooled + (size_t)b*8*NPOOL;

    for (int i = threadIdx.x; i < 8*361; i += 256) {
        int c = i / 361; int r = i - c*361; int lh = r / 19, lw = r - lh*19;
        int ph = h0 + lh - 1, pw = w0 + lw - 1;
        float v = 0.f;
        if (ph >= 0 && ph < HP && pw >= 0 && pw < WP)
            v = pb[c*NPOOL + ph*WP + pw];
        T[c][lh][lw] = v;
    }
    __syncthreads();

    float s2 = 0.f;
    #pragma unroll
    for (int c = 0; c < 8; ++c)
        #pragma unroll
        for (int i = 0; i < 4; ++i)
            #pragma unroll
            for (int j = 0; j < 4; ++j) {
                float u = T[c][ty+i][tx+j];
                s2 += u*u;
            }
    float inv1 = 1.0f / fmaxf(sqrtf(s2), 1e-12f);

    float sv2 = 0.f, sv1 = 0.f;
    #pragma unroll
    for (int c = 0; c < 8; ++c)
        #pragma unroll
        for (int i = 0; i < 4; ++i)
            #pragma unroll
            for (int j = 0; j < 4; ++j) {
                float u = T[c][ty+i][tx+j];
                float v = fminf(u*inv1, 0.2f);
                sv2 += v*v; sv1 += v;
            }
    float inv2  = 1.0f / fmaxf(sqrtf(sv2), 1e-12f);
    float invl1 = 1.0f / fmaxf(sv1 * inv2, 1e-12f);

    int outv[64];
    #pragma unroll
    for (int c = 0; c < 8; ++c)
        #pragma unroll
        for (int i = 0; i < 4; ++i)
            #pragma unroll
            for (int jj = 0; jj < 2; ++jj) {
                float u0 = T[c][ty+i][tx+jj*2];
                float u1 = T[c][ty+i][tx+jj*2+1];
                float v0 = fminf(u0*inv1, 0.2f) * inv2;
                float v1 = fminf(u1*inv1, 0.2f) * inv2;
                float fo0 = sqrtf(v0*invl1 + 1e-10f);
                float fo1 = sqrtf(v1*invl1 + 1e-10f);
                bf16 hb0 = __float2bfloat16(fo0);
                bf16 hb1 = __float2bfloat16(fo1);
                unsigned lo = *reinterpret_cast<unsigned short*>(&hb0);
                unsigned hi = *reinterpret_cast<unsigned short*>(&hb1);
                outv[c*8 + i*2 + jj] = (int)(lo | (hi << 16));
            }

    int h = h0 + ty, w = w0 + tx;
    if (h < HH) {
        int4* fb = reinterpret_cast<int4*>(f2 + ((size_t)b*NPIX + h*WW + w)*128);
        #pragma unroll
        for (int q = 0; q < 16; ++q) {
            int4 v4;
            v4.x = outv[q*4]; v4.y = outv[q*4+1]; v4.z = outv[q*4+2]; v4.w = outv[q*4+3];
            fb[q] = v4;
        }
    }
}

// ---------------------------------------------------------------------------
// conv1 v2: MFMA implicit GEMM, 128->32 ch, 5x5, pad 2, ReLU.
// Block: 32 out-ch x 128 px x 2 output rows. 4 waves; wave wv: output row
// r=wv>>1, px half p0=(wv&1)*64 (2 N-subtiles of 32 px). mfma_32x32x16_bf16:
// M=32 (all out-ch), K=16 (kh halves of 32-ch chunk). LDS tile [6][132][40].
__global__ __launch_bounds__(256) void k_conv1(const short* __restrict__ f2,
        const short* __restrict__ apack, const float* __restrict__ bias,
        float* __restrict__ out) {
    __shared__ short S[6][132][40];   // 63,360 B
    const int tid = threadIdx.x;
    const int l   = tid & 63;
    const int wv  = tid >> 6;
    const int h0  = blockIdx.y * 2;
    const int w0  = blockIdx.x * 128;
    const int b   = blockIdx.z;
    const int r   = wv >> 1;          // output row within block
    const int p0  = (wv & 1) * 64;    // px base within 128
    const int c32 = l & 31;           // px within 32-wide N-tile (B col / D col)
    const int ksel = l >> 5;          // k-subgroup

    f32x16 acc0 = {0.f};
    f32x16 acc1 = {0.f};

    for (int cc = 0; cc < 4; ++cc) {
        __syncthreads();
        // stage rows h0-2 .. h0+3, 132 px, 32 ch; div-free mapping.
        #pragma unroll
        for (int ky = 0; ky < 6; ++ky) {
            for (int i2 = tid; i2 < 528; i2 += 256) {
                int q = i2 & 3, px = i2 >> 2;
                int gh = h0 + ky - 2, gw = w0 + px - 2;
                int4 v = {0,0,0,0};
                if (gh >= 0 && gh < HH && gw >= 0 && gw < WW)
                    v = *reinterpret_cast<const int4*>(
                          f2 + (((size_t)b*HH + gh)*WW + gw)*128 + cc*32 + q*8);
                *reinterpret_cast<int4*>(&S[ky][px][q*8]) = v;
            }
        }
        __syncthreads();

        #pragma unroll
        for (int ky = 0; ky < 5; ++ky) {
            #pragma unroll
            for (int kx = 0; kx < 5; ++kx) {
                #pragma unroll
                for (int kh = 0; kh < 2; ++kh) {
                    const short* ap = apack +
                        ((((size_t)(cc*25 + ky*5 + kx))*2 + kh)*64 + l)*8;
                    short8v a = *reinterpret_cast<const short8v*>(ap);
                    const short* bp = &S[r + ky][p0 + c32 + kx][kh*16 + ksel*8];
                    short8v b0 = *reinterpret_cast<const short8v*>(bp);
                    short8v b1 = *reinterpret_cast<const short8v*>(bp + 32*40);
                    acc0 = __builtin_amdgcn_mfma_f32_32x32x16_bf16(a, b0, acc0, 0, 0, 0);
                    acc1 = __builtin_amdgcn_mfma_f32_32x32x16_bf16(a, b1, acc1, 0, 0, 0);
                }
            }
        }
    }

    // D layout (m74/m101): col = lane&31, row = (reg&3) + 8*(reg>>2) + 4*(lane>>5)
    const int h  = h0 + r;
    const int px = w0 + p0 + c32;
    #pragma unroll
    for (int reg = 0; reg < 16; ++reg) {
        int o = (reg & 3) + 8*(reg >> 2) + 4*ksel;
        float bv = bias[o];
        float* op = out + ((size_t)b*32 + o)*NPIX + h*WW + px;
        op[0]  = fmaxf(acc0[reg] + bv, 0.f);
        op[32] = fmaxf(acc1[reg] + bv, 0.f);
    }
}

// ---------------------------------------------------------------------------
// conv2: 32->8, 3x3, pad 1, ReLU.
__global__ __launch_bounds__(256) void k_conv2(const float* __restrict__ in,
        const float* __restrict__ wT, const float* __restrict__ bias,
        float* __restrict__ out) {
    __shared__ float tile[8][18][18];
    int tx = threadIdx.x & 15, ty = threadIdx.x >> 4;
    int h0 = blockIdx.y * 16, w0 = blockIdx.x * 16, b = blockIdx.z;
    float acc[8];
    #pragma unroll
    for (int o = 0; o < 8; ++o) acc[o] = 0.f;

    for (int cc = 0; cc < 4; ++cc) {
        __syncthreads();
        for (int t = threadIdx.x; t < 8*324; t += 256) {
            int c = t / 324; int r = t - c*324; int lh = r / 18, lw = r - lh*18;
            int gh = h0 + lh - 1, gw = w0 + lw - 1;
            float v = 0.f;
            if (gh >= 0 && gh < HH && gw >= 0 && gw < WW)
                v = in[((size_t)(b*32 + cc*8 + c))*NPIX + gh*WW + gw];
            tile[c][lh][lw] = v;
        }
        __syncthreads();
        for (int c = 0; c < 8; ++c) {
            #pragma unroll
            for (int ky = 0; ky < 3; ++ky) {
                #pragma unroll
                for (int kx = 0; kx < 3; ++kx) {
                    float v = tile[c][ty+ky][tx+kx];
                    const float* wp = wT + (((cc*8+c)*9) + ky*3 + kx)*8;
                    #pragma unroll
                    for (int o = 0; o < 8; ++o) acc[o] = fmaf(v, wp[o], acc[o]);
                }
            }
        }
    }
    int h = h0 + ty, w = w0 + tx;
    if (h < HH) {
        float* op = out + (size_t)b*8*NPIX + h*WW + w;
        #pragma unroll
        for (int o = 0; o < 8; ++o) op[(size_t)o*NPIX] = fmaxf(acc[o] + bias[o], 0.f);
    }
}

// ---------------------------------------------------------------------------
// conv3: 8->2, 5x5, pad 2, no activation.
__global__ __launch_bounds__(256) void k_conv3(const float* __restrict__ in,
        const float* __restrict__ wT, const float* __restrict__ bias,
        float* __restrict__ out) {
    __shared__ float tile[8][20][20];
    int tx = threadIdx.x & 15, ty = threadIdx.x >> 4;
    int h0 = blockIdx.y * 16, w0 = blockIdx.x * 16, b = blockIdx.z;
    float acc0 = 0.f, acc1 = 0.f;

    for (int t = threadIdx.x; t < 8*400; t += 256) {
        int c = t / 400; int r = t - c*400; int lh = r / 20, lw = r - lh*20;
        int gh = h0 + lh - 2, gw = w0 + lw - 2;
        float v = 0.f;
        if (gh >= 0 && gh < HH && gw >= 0 && gw < WW)
            v = in[((size_t)(b*8 + c))*NPIX + gh*WW + gw];
        tile[c][lh][lw] = v;
    }
    __syncthreads();
    for (int c = 0; c < 8; ++c) {
        for (int ky = 0; ky < 5; ++ky) {
            #pragma unroll
            for (int kx = 0; kx < 5; ++kx) {
                float v = tile[c][ty+ky][tx+kx];
                const float* wp = wT + ((c*25) + ky*5 + kx)*2;
                acc0 = fmaf(v, wp[0], acc0);
                acc1 = fmaf(v, wp[1], acc1);
            }
        }
    }
    int h = h0 + ty, w = w0 + tx;
    if (h < HH) {
        float* op = out + (size_t)b*2*NPIX + h*WW + w;
        op[0]    = acc0 + bias[0];
        op[NPIX] = acc1 + bias[1];
    }
}

// ---------------------------------------------------------------------------
__device__ __forceinline__ int refl(int i, int n) {
    if (i < 0) i = -i;
    if (i >= n) i = 2*n - 2 - i;
    return i;
}

__global__ void k_bilat(const float* __restrict__ c3, const float* __restrict__ x,
                        float* __restrict__ outb) {
    int idx = blockIdx.x * blockDim.x + threadIdx.x;
    if (idx >= BB*NPIX) return;
    int b = idx / NPIX;
    int p = idx - b*NPIX;
    int h = p / WW, w = p - h*WW;
    const float* xb = x + (size_t)b*NPIX;
    const float* f0 = c3 + (size_t)b*2*NPIX;
    const float* f1 = f0 + NPIX;

    float e1 = expf(-1.0f/4.5f), e2 = expf(-4.0f/4.5f);
    float sden = 1.0f + 2.f*e1 + 2.f*e2;
    float g1v[5] = { e2/sden, e1/sden, 1.0f/sden, e1/sden, e2/sden };

    float g = xb[p];
    float num0 = 0.f, num1 = 0.f, den = 0.f;
    #pragma unroll
    for (int dy = 0; dy < 5; ++dy) {
        int hh = refl(h + dy - 2, HH);
        #pragma unroll
        for (int dx = 0; dx < 5; ++dx) {
            int wc = refl(w + dx - 2, WW);
            float gs = xb[hh*WW + wc];
            float d = gs - g;
            float k = g1v[dy] * g1v[dx] * expf(-200.0f * d * d);
            num0 += f0[hh*WW + wc] * k;
            num1 += f1[hh*WW + wc] * k;
            den  += k;
        }
    }
    float invd = 1.0f / den;
    outb[(size_t)b*2*NPIX + p]        = num0 * invd;
    outb[(size_t)b*2*NPIX + NPIX + p] = num1 * invd;
}

// ---------------------------------------------------------------------------
__global__ void k_minmax1(const float* __restrict__ blur, float4* __restrict__ partial) {
    float umin = 3.0e38f, umax = -3.0e38f, vmin = 3.0e38f, vmax = -3.0e38f;
    for (int i = blockIdx.x*blockDim.x + threadIdx.x; i < BB*NPIX; i += gridDim.x*blockDim.x) {
        int b = i / NPIX; int p = i - b*NPIX;
        float u = blur[(size_t)b*2*NPIX + p];
        float v = blur[(size_t)b*2*NPIX + NPIX + p];
        umin = fminf(umin, u); umax = fmaxf(umax, u);
        vmin = fminf(vmin, v); vmax = fmaxf(vmax, v);
    }
    #pragma unroll
    for (int off = 32; off > 0; off >>= 1) {
        umin = fminf(umin, __shfl_down(umin, off));
        umax = fmaxf(umax, __shfl_down(umax, off));
        vmin = fminf(vmin, __shfl_down(vmin, off));
        vmax = fmaxf(vmax, __shfl_down(vmax, off));
    }
    __shared__ float4 sm[4];
    int lane = threadIdx.x & 63, wid = threadIdx.x >> 6;
    if (lane == 0) sm[wid] = make_float4(umin, umax, vmin, vmax);
    __syncthreads();
    if (threadIdx.x == 0) {
        float4 r = sm[0];
        for (int k = 1; k < 4; ++k) {
            r.x = fminf(r.x, sm[k].x); r.y = fmaxf(r.y, sm[k].y);
            r.z = fminf(r.z, sm[k].z); r.w = fmaxf(r.w, sm[k].w);
        }
        partial[blockIdx.x] = r;
    }
}

__global__ void k_minmax2(const float4* __restrict__ partial, float* __restrict__ sc) {
    float4 p = partial[threadIdx.x];
    #pragma unroll
    for (int off = 32; off > 0; off >>= 1) {
        p.x = fminf(p.x, __shfl_down(p.x, off));
        p.y = fmaxf(p.y, __shfl_down(p.y, off));
        p.z = fminf(p.z, __shfl_down(p.z, off));
        p.w = fmaxf(p.w, __shfl_down(p.w, off));
    }
    __shared__ float4 sm[2];
    if ((threadIdx.x & 63) == 0) sm[threadIdx.x >> 6] = p;
    __syncthreads();
    if (threadIdx.x == 0) {
        sc[0] = fminf(sm[0].x, sm[1].x);
        sc[1] = fmaxf(sm[0].y, sm[1].y);
        sc[2] = fminf(sm[0].z, sm[1].z);
        sc[3] = fmaxf(sm[0].w, sm[1].w);
    }
}

__global__ void k_final(const float* __restrict__ blur, const float* __restrict__ x,
                        const float* __restrict__ sc, float* __restrict__ out) {
    int idx = blockIdx.x * blockDim.x + threadIdx.x;
    if (idx >= BB*NPIX) return;
    int b = idx / NPIX;
    int p = idx - b*NPIX;
    float umin = sc[0], umax = sc[1], vmin = sc[2], vmax = sc[3];
    float u = blur[(size_t)b*2*NPIX + p];
    float v = blur[(size_t)b*2*NPIX + NPIX + p];
    u = fminf(fmaxf((u - umin) / (umax - umin + 1e-6f), 0.f), 1.f) * 0.872f - 0.436f;
    v = fminf(fmaxf((v - vmin) / (vmax - vmin + 1e-6f), 0.f), 1.f) * 1.23f  - 0.615f;
    float y = x[(size_t)b*NPIX + p];
    out[(size_t)(b*3+0)*NPIX + p] = y + 1.14f*v;
    out[(size_t)(b*3+1)*NPIX + p] = y - 0.396f*u - 0.581f*v;
    out[(size_t)(b*3+2)*NPIX + p] = y + 2.029f*u;
}

// ---------------------------------------------------------------------------
extern "C" void kernel_launch(void* const* d_in, const int* in_sizes, int n_in,
                              void* d_out, int out_size, void* d_ws, size_t ws_size,
                              hipStream_t stream) {
    const float* x  = (const float*)d_in[0];
    const float* w1 = (const float*)d_in[1];
    const float* b1 = (const float*)d_in[2];
    const float* w2 = (const float*)d_in[3];
    const float* b2 = (const float*)d_in[4];
    const float* w3 = (const float*)d_in[5];
    const float* b3 = (const float*)d_in[6];
    float* out = (float*)d_out;
    char* ws = (char*)d_ws;

    const size_t POOLED_OFF = 0;                      // 17,794,944
    const size_t X_OFF      = 17795072;
    const size_t Y_OFF      = X_OFF + 141557760;      // c1out f32: 70,778,880
    const size_t AP_OFF     = Y_OFF + 70778880;       // apack bf16: 204,800
    const size_t WT2_OFF    = AP_OFF + 409600;        // 9,216
    const size_t WT3_OFF    = WT2_OFF + 9216;         // 3,200
    const size_t PART_OFF   = WT3_OFF + 3328;         // 128 * 16
    const size_t SC_OFF     = PART_OFF + 2048;        // 16

    float*  pooled = (float*)(ws + POOLED_OFF);
    short*  f2     = (short*)(ws + X_OFF);
    float*  c2o    = (float*)(ws + X_OFF);
    float*  c3o    = (float*)(ws + X_OFF + 24000000);
    float*  blur   = (float*)(ws + X_OFF + 32000000);
    float*  c1o    = (float*)(ws + Y_OFF);
    short*  apack  = (short*)(ws + AP_OFF);
    float*  wT2    = (float*)(ws + WT2_OFF);
    float*  wT3    = (float*)(ws + WT3_OFF);
    float4* part   = (float4*)(ws + PART_OFF);
    float*  sc     = (float*)(ws + SC_OFF);

    k_wprep<<<512, 256, 0, stream>>>(w1, w2, w3, apack, wT2, wT3);

    dim3 pg((WP + 15)/16, (HP + 15)/16, BB);   // 33 x 17 x 4
    k_pool<<<pg, 256, 0, stream>>>(x, pooled);

    dim3 fg(WW/16, (HH + 15)/16, BB);          // 32 x 17 x 4
    k_feat<<<fg, 256, 0, stream>>>(pooled, f2);

    dim3 cg1(WW/128, HH/2, BB);                // 4 x 135 x 4
    k_conv1<<<cg1, 256, 0, stream>>>(f2, apack, b1, c1o);

    dim3 cg(WW/16, (HH + 15)/16, BB);          // 32 x 17 x 4
    k_conv2<<<cg, 256, 0, stream>>>(c1o, wT2, b2, c2o);
    k_conv3<<<cg, 256, 0, stream>>>(c2o, wT3, b3, c3o);

    k_bilat<<<(BB*NPIX + 255)/256, 256, 0, stream>>>(c3o, x, blur);
    k_minmax1<<<128, 256, 0, stream>>>(blur, part);
    k_minmax2<<<1, 128, 0, stream>>>(part, sc);
    k_final<<<(BB*NPIX + 255)/256, 256, 0, stream>>>(blur, x, sc, out);
}

// Round 5
// 385.191 us; speedup vs baseline: 9.1779x; 1.1828x over previous
//
#include <hip/hip_runtime.h>
#include <hip/hip_bf16.h>

typedef __hip_bfloat16 bf16;
typedef __attribute__((ext_vector_type(8))) short short8v;
typedef __attribute__((ext_vector_type(16))) float f32x16;

#define HH 270
#define WW 512
#define BB 4
#define HP 271
#define WP 513
#define NPIX (HH*WW)      // 138240
#define NPOOL (HP*WP)     // 139023
#define TWO_PI 6.28318530717958647692f

// ---------------------------------------------------------------------------
// Weight prep + zero-page init.
//  - apack: conv1 weights bf16, mfma_f32_32x32x16_bf16 A-frag order:
//      [cc 4][ky 5][kx 5][kh 2][lane 64][j 8]
//      A[row = lane&31][k = (lane>>5)*8 + j], in-ch = cc*32 + kh*16 + k
//  - wT2/wT3: f32 [CK][O] transposes.
//  - zp: 4 KB zero page (global_load_lds OOB redirect target). Zeroed every
//    launch => deterministic.
__global__ void k_wprep(const float* __restrict__ w1, const float* __restrict__ w2,
                        const float* __restrict__ w3, short* __restrict__ apack,
                        float* __restrict__ wT2, float* __restrict__ wT3,
                        float* __restrict__ zp) {
    int stride = gridDim.x * blockDim.x;
    int t0 = blockIdx.x * blockDim.x + threadIdx.x;
    for (int i = t0; i < 1024; i += stride) zp[i] = 0.f;
    for (int i = t0; i < 4*25*2*64*8; i += stride) {
        int idx = i;
        int j    = idx & 7;  idx >>= 3;
        int lane = idx & 63; idx >>= 6;
        int kh   = idx & 1;  idx >>= 1;
        int t    = idx % 25;
        int cc   = idx / 25;
        int o = lane & 31;
        int c = cc*32 + kh*16 + (lane >> 5)*8 + j;
        float v = w1[o*3200 + c*25 + t];
        bf16 h = __float2bfloat16(v);
        apack[i] = *reinterpret_cast<short*>(&h);
    }
    for (int i = t0; i < 288*8;  i += stride) { int ck = i >> 3, o = i & 7;  wT2[i] = w2[o*288  + ck]; }
    for (int i = t0; i < 200*2;  i += stride) { int ck = i >> 1, o = i & 1;  wT3[i] = w3[o*200  + ck]; }
}

// ---------------------------------------------------------------------------
// Tiled pool: per-pixel grad/atan2/soft-bin ONCE into 8-ch LDS histogram,
// then 4x4 window sum per output pixel.
__global__ __launch_bounds__(256) void k_pool(const float* __restrict__ x,
                                              float* __restrict__ pooled) {
    __shared__ float hist[8][19][20];
    const int tx = threadIdx.x & 15, ty = threadIdx.x >> 4;
    const int j0 = blockIdx.x * 16, i0 = blockIdx.y * 16, b = blockIdx.z;
    const float* xb = x + (size_t)b * NPIX;

    for (int i = threadIdx.x; i < 8*19*20; i += 256) ((float*)hist)[i] = 0.f;
    __syncthreads();

    for (int i = threadIdx.x; i < 361; i += 256) {
        int lh = i / 19, lw = i - lh*19;
        int hh = i0 + lh - 2, ww = j0 + lw - 2;
        if (hh >= 0 && hh < HH && ww >= 0 && ww < WW) {
            float gx = xb[hh*WW + (ww+1 < WW ? ww+1 : WW-1)] - xb[hh*WW + (ww-1 >= 0 ? ww-1 : 0)];
            float gy = xb[(hh+1 < HH ? hh+1 : HH-1)*WW + ww] - xb[(hh-1 >= 0 ? hh-1 : 0)*WW + ww];
            float mag  = sqrtf(gx*gx + gy*gy + 1e-10f);
            float ori  = atan2f(gy, gx + 1e-10f) + TWO_PI;
            float obig = ori * (8.0f / TWO_PI);
            float b0f  = floorf(obig);
            float wo1  = obig - b0f;
            int ib0 = ((int)b0f) & 7;
            int ib1 = (ib0 + 1) & 7;
            hist[ib0][lh][lw] += (1.0f - wo1) * mag;
            hist[ib1][lh][lw] += wo1 * mag;
        }
    }
    __syncthreads();

    int i = i0 + ty, j = j0 + tx;
    if (i < HP && j < WP) {
        float a[8];
        #pragma unroll
        for (int c = 0; c < 8; ++c) a[c] = 0.f;
        #pragma unroll
        for (int di = 0; di < 4; ++di)
            #pragma unroll
            for (int dj = 0; dj < 4; ++dj) {
                #pragma unroll
                for (int c = 0; c < 8; ++c)
                    a[c] += hist[c][ty+di][tx+dj];
            }
        float* pb = pooled + (size_t)b*8*NPOOL + i*WP + j;
        const float s = 1.0f/16.0f;
        #pragma unroll
        for (int c = 0; c < 8; ++c) pb[c*NPOOL] = a[c]*s;
    }
}

// ---------------------------------------------------------------------------
// SIFT normalize, tiled; channels-last bf16 output, burst dwordx4 writes.
__global__ __launch_bounds__(256) void k_feat(const float* __restrict__ pooled,
                                              short* __restrict__ f2) {
    __shared__ float T[8][19][19];
    const int tx = threadIdx.x & 15, ty = threadIdx.x >> 4;
    const int w0 = blockIdx.x * 16, h0 = blockIdx.y * 16, b = blockIdx.z;
    const float* pb = pooled + (size_t)b*8*NPOOL;

    for (int i = threadIdx.x; i < 8*361; i += 256) {
        int c = i / 361; int r = i - c*361; int lh = r / 19, lw = r - lh*19;
        int ph = h0 + lh - 1, pw = w0 + lw - 1;
        float v = 0.f;
        if (ph >= 0 && ph < HP && pw >= 0 && pw < WP)
            v = pb[c*NPOOL + ph*WP + pw];
        T[c][lh][lw] = v;
    }
    __syncthreads();

    float s2 = 0.f;
    #pragma unroll
    for (int c = 0; c < 8; ++c)
        #pragma unroll
        for (int i = 0; i < 4; ++i)
            #pragma unroll
            for (int j = 0; j < 4; ++j) {
                float u = T[c][ty+i][tx+j];
                s2 += u*u;
            }
    float inv1 = 1.0f / fmaxf(sqrtf(s2), 1e-12f);

    float sv2 = 0.f, sv1 = 0.f;
    #pragma unroll
    for (int c = 0; c < 8; ++c)
        #pragma unroll
        for (int i = 0; i < 4; ++i)
            #pragma unroll
            for (int j = 0; j < 4; ++j) {
                float u = T[c][ty+i][tx+j];
                float v = fminf(u*inv1, 0.2f);
                sv2 += v*v; sv1 += v;
            }
    float inv2  = 1.0f / fmaxf(sqrtf(sv2), 1e-12f);
    float invl1 = 1.0f / fmaxf(sv1 * inv2, 1e-12f);

    int outv[64];
    #pragma unroll
    for (int c = 0; c < 8; ++c)
        #pragma unroll
        for (int i = 0; i < 4; ++i)
            #pragma unroll
            for (int jj = 0; jj < 2; ++jj) {
                float u0 = T[c][ty+i][tx+jj*2];
                float u1 = T[c][ty+i][tx+jj*2+1];
                float v0 = fminf(u0*inv1, 0.2f) * inv2;
                float v1 = fminf(u1*inv1, 0.2f) * inv2;
                float fo0 = sqrtf(v0*invl1 + 1e-10f);
                float fo1 = sqrtf(v1*invl1 + 1e-10f);
                bf16 hb0 = __float2bfloat16(fo0);
                bf16 hb1 = __float2bfloat16(fo1);
                unsigned lo = *reinterpret_cast<unsigned short*>(&hb0);
                unsigned hi = *reinterpret_cast<unsigned short*>(&hb1);
                outv[c*8 + i*2 + jj] = (int)(lo | (hi << 16));
            }

    int h = h0 + ty, w = w0 + tx;
    if (h < HH) {
        int4* fb = reinterpret_cast<int4*>(f2 + ((size_t)b*NPIX + h*WW + w)*128);
        #pragma unroll
        for (int q = 0; q < 16; ++q) {
            int4 v4;
            v4.x = outv[q*4]; v4.y = outv[q*4+1]; v4.z = outv[q*4+2]; v4.w = outv[q*4+3];
            fb[q] = v4;
        }
    }
}

// ---------------------------------------------------------------------------
// conv1 v3: MFMA implicit GEMM, 128->32 ch, 5x5, pad 2, ReLU.
// Block: 4 output rows x 128 px, 4 waves (wave wv = row wv, all 128 px as
// 4 N-subtiles of 32). mfma_32x32x16: 4 MFMA per A-load. LDS [8][136][32]
// bf16, linear rows staged by global_load_lds(16B) with a 16B-group rotation
// swizzle pre-applied on the GLOBAL source (rule #21: linear dest +
// inverse-swz source + swz read) -> same bank pattern as pad-40 layout.
// OOB lanes load from zero page. Output: bf16 [b][h][q4][w][8ch] packed 8B
// stores (dense 512B wave segments).
__global__ __launch_bounds__(256) void k_conv1(const short* __restrict__ f2,
        const short* __restrict__ apack, const float* __restrict__ bias,
        short* __restrict__ c1o, const float* __restrict__ zp) {
    __shared__ short S[8][136][32];   // 69,632 B
    const int tid = threadIdx.x;
    const int l   = tid & 63;
    const int wv  = tid >> 6;         // output row within block
    const int h0  = blockIdx.y * 4;
    const int w0  = blockIdx.x * 128;
    const int b   = blockIdx.z;
    const int c32 = l & 31;           // px within 32-wide N-tile (B col / D col)
    const int ksel = l >> 5;          // k-subgroup

    f32x16 acc0 = {0.f};
    f32x16 acc1 = {0.f};
    f32x16 acc2 = {0.f};
    f32x16 acc3 = {0.f};

    for (int cc = 0; cc < 4; ++cc) {
        __syncthreads();
        // Stage 8 rows x 136 px x 32 ch via LDS-DMA. Slot s=(ky*136+px)*4+q
        // holds 16B group g=(q-px)&3 of pixel px => read at slot (g+px)&3.
        // 4352 slots = 17 * 256 -> always full waves.
        for (int s = tid; s < 4352; s += 256) {
            int ky = s / 544;
            int r  = s - ky*544;
            int px = r >> 2;
            int q  = r & 3;
            int g  = (q - px) & 3;
            int gh = h0 + ky - 2, gw = w0 + px - 2;
            const void* src = (gh >= 0 && gh < HH && gw >= 0 && gw < WW)
                ? (const void*)(f2 + (((size_t)b*HH + gh)*WW + gw)*128 + cc*32 + g*8)
                : (const void*)zp;
            short* dst = &S[0][0][0] + (size_t)(s & ~63) * 8;  // wave-uniform base
            __builtin_amdgcn_global_load_lds(
                (const __attribute__((address_space(1))) void*)src,
                (__attribute__((address_space(3))) void*)dst, 16, 0, 0);
        }
        asm volatile("s_waitcnt vmcnt(0)");
        __syncthreads();

        #pragma unroll
        for (int ky = 0; ky < 5; ++ky) {
            #pragma unroll
            for (int kx = 0; kx < 5; ++kx) {
                #pragma unroll
                for (int kh = 0; kh < 2; ++kh) {
                    const short* ap = apack +
                        ((((size_t)(cc*25 + ky*5 + kx))*2 + kh)*64 + l)*8;
                    short8v a = *reinterpret_cast<const short8v*>(ap);
                    const int rot = ((kh*2 + ksel) + c32 + kx) & 3;
                    const short* brow = &S[wv + ky][0][0] + (c32 + kx)*32 + rot*8;
                    short8v b0 = *reinterpret_cast<const short8v*>(brow);
                    short8v b1 = *reinterpret_cast<const short8v*>(brow + 32*32);
                    short8v b2 = *reinterpret_cast<const short8v*>(brow + 64*32);
                    short8v b3 = *reinterpret_cast<const short8v*>(brow + 96*32);
                    acc0 = __builtin_amdgcn_mfma_f32_32x32x16_bf16(a, b0, acc0, 0, 0, 0);
                    acc1 = __builtin_amdgcn_mfma_f32_32x32x16_bf16(a, b1, acc1, 0, 0, 0);
                    acc2 = __builtin_amdgcn_mfma_f32_32x32x16_bf16(a, b2, acc2, 0, 0, 0);
                    acc3 = __builtin_amdgcn_mfma_f32_32x32x16_bf16(a, b3, acc3, 0, 0, 0);
                }
            }
        }
    }

    // D layout: col(px)=lane&31, out-ch o = (reg&3) + 8*(reg>>2) + 4*ksel.
    // c1o[b][h][q][w][8]: lane packs 4 bf16 (8B) per quad q.
    const int h = h0 + wv;
    if (h < HH) {
        const size_t rowbase = ((size_t)b*HH + h)*4;
        #pragma unroll
        for (int nt = 0; nt < 4; ++nt) {
            const f32x16& A = (nt==0) ? acc0 : (nt==1) ? acc1 : (nt==2) ? acc2 : acc3;
            int px = w0 + nt*32 + c32;
            #pragma unroll
            for (int q = 0; q < 4; ++q) {
                short4 pk;
                short* pkp = (short*)&pk;
                #pragma unroll
                for (int j = 0; j < 4; ++j) {
                    float v = fmaxf(A[q*4 + j] + bias[q*8 + 4*ksel + j], 0.f);
                    bf16 hb = __float2bfloat16(v);
                    pkp[j] = *reinterpret_cast<short*>(&hb);
                }
                *reinterpret_cast<short4*>(c1o + ((rowbase + q)*WW + px)*8 + ksel*4) = pk;
            }
        }
    }
}

// ---------------------------------------------------------------------------
// conv2: 32->8, 3x3, pad 1, ReLU. Input bf16 [b][h][q][w][8].
__global__ __launch_bounds__(256) void k_conv2(const short* __restrict__ in,
        const float* __restrict__ wT, const float* __restrict__ bias,
        float* __restrict__ out) {
    __shared__ float tile[8][18][18];
    int tx = threadIdx.x & 15, ty = threadIdx.x >> 4;
    int h0 = blockIdx.y * 16, w0 = blockIdx.x * 16, b = blockIdx.z;
    float acc[8];
    #pragma unroll
    for (int o = 0; o < 8; ++o) acc[o] = 0.f;

    for (int cc = 0; cc < 4; ++cc) {
        __syncthreads();
        for (int t = threadIdx.x; t < 324; t += 256) {
            int lh = t / 18, lw = t - lh*18;
            int gh = h0 + lh - 1, gw = w0 + lw - 1;
            if (gh >= 0 && gh < HH && gw >= 0 && gw < WW) {
                short8v v = *reinterpret_cast<const short8v*>(
                    in + (((size_t)b*HH + gh)*4 + cc)*WW*8 + (size_t)gw*8);
                #pragma unroll
                for (int c = 0; c < 8; ++c) {
                    unsigned u = ((unsigned)(unsigned short)v[c]) << 16;
                    tile[c][lh][lw] = *reinterpret_cast<float*>(&u);
                }
            } else {
                #pragma unroll
                for (int c = 0; c < 8; ++c) tile[c][lh][lw] = 0.f;
            }
        }
        __syncthreads();
        for (int c = 0; c < 8; ++c) {
            #pragma unroll
            for (int ky = 0; ky < 3; ++ky) {
                #pragma unroll
                for (int kx = 0; kx < 3; ++kx) {
                    float v = tile[c][ty+ky][tx+kx];
                    const float* wp = wT + (((cc*8+c)*9) + ky*3 + kx)*8;
                    #pragma unroll
                    for (int o = 0; o < 8; ++o) acc[o] = fmaf(v, wp[o], acc[o]);
                }
            }
        }
    }
    int h = h0 + ty, w = w0 + tx;
    if (h < HH) {
        float* op = out + (size_t)b*8*NPIX + h*WW + w;
        #pragma unroll
        for (int o = 0; o < 8; ++o) op[(size_t)o*NPIX] = fmaxf(acc[o] + bias[o], 0.f);
    }
}

// ---------------------------------------------------------------------------
// conv3: 8->2, 5x5, pad 2, no activation.
__global__ __launch_bounds__(256) void k_conv3(const float* __restrict__ in,
        const float* __restrict__ wT, const float* __restrict__ bias,
        float* __restrict__ out) {
    __shared__ float tile[8][20][20];
    int tx = threadIdx.x & 15, ty = threadIdx.x >> 4;
    int h0 = blockIdx.y * 16, w0 = blockIdx.x * 16, b = blockIdx.z;
    float acc0 = 0.f, acc1 = 0.f;

    for (int t = threadIdx.x; t < 8*400; t += 256) {
        int c = t / 400; int r = t - c*400; int lh = r / 20, lw = r - lh*20;
        int gh = h0 + lh - 2, gw = w0 + lw - 2;
        float v = 0.f;
        if (gh >= 0 && gh < HH && gw >= 0 && gw < WW)
            v = in[((size_t)(b*8 + c))*NPIX + gh*WW + gw];
        tile[c][lh][lw] = v;
    }
    __syncthreads();
    for (int c = 0; c < 8; ++c) {
        for (int ky = 0; ky < 5; ++ky) {
            #pragma unroll
            for (int kx = 0; kx < 5; ++kx) {
                float v = tile[c][ty+ky][tx+kx];
                const float* wp = wT + ((c*25) + ky*5 + kx)*2;
                acc0 = fmaf(v, wp[0], acc0);
                acc1 = fmaf(v, wp[1], acc1);
            }
        }
    }
    int h = h0 + ty, w = w0 + tx;
    if (h < HH) {
        float* op = out + (size_t)b*2*NPIX + h*WW + w;
        op[0]    = acc0 + bias[0];
        op[NPIX] = acc1 + bias[1];
    }
}

// ---------------------------------------------------------------------------
__device__ __forceinline__ int refl(int i, int n) {
    if (i < 0) i = -i;
    if (i >= n) i = 2*n - 2 - i;
    return i;
}

__global__ void k_bilat(const float* __restrict__ c3, const float* __restrict__ x,
                        float* __restrict__ outb) {
    int idx = blockIdx.x * blockDim.x + threadIdx.x;
    if (idx >= BB*NPIX) return;
    int b = idx / NPIX;
    int p = idx - b*NPIX;
    int h = p / WW, w = p - h*WW;
    const float* xb = x + (size_t)b*NPIX;
    const float* f0 = c3 + (size_t)b*2*NPIX;
    const float* f1 = f0 + NPIX;

    float e1 = expf(-1.0f/4.5f), e2 = expf(-4.0f/4.5f);
    float sden = 1.0f + 2.f*e1 + 2.f*e2;
    float g1v[5] = { e2/sden, e1/sden, 1.0f/sden, e1/sden, e2/sden };

    float g = xb[p];
    float num0 = 0.f, num1 = 0.f, den = 0.f;
    #pragma unroll
    for (int dy = 0; dy < 5; ++dy) {
        int hh = refl(h + dy - 2, HH);
        #pragma unroll
        for (int dx = 0; dx < 5; ++dx) {
            int wc = refl(w + dx - 2, WW);
            float gs = xb[hh*WW + wc];
            float d = gs - g;
            float k = g1v[dy] * g1v[dx] * expf(-200.0f * d * d);
            num0 += f0[hh*WW + wc] * k;
            num1 += f1[hh*WW + wc] * k;
            den  += k;
        }
    }
    float invd = 1.0f / den;
    outb[(size_t)b*2*NPIX + p]        = num0 * invd;
    outb[(size_t)b*2*NPIX + NPIX + p] = num1 * invd;
}

// ---------------------------------------------------------------------------
__global__ void k_minmax1(const float* __restrict__ blur, float4* __restrict__ partial) {
    float umin = 3.0e38f, umax = -3.0e38f, vmin = 3.0e38f, vmax = -3.0e38f;
    for (int i = blockIdx.x*blockDim.x + threadIdx.x; i < BB*NPIX; i += gridDim.x*blockDim.x) {
        int b = i / NPIX; int p = i - b*NPIX;
        float u = blur[(size_t)b*2*NPIX + p];
        float v = blur[(size_t)b*2*NPIX + NPIX + p];
        umin = fminf(umin, u); umax = fmaxf(umax, u);
        vmin = fminf(vmin, v); vmax = fmaxf(vmax, v);
    }
    #pragma unroll
    for (int off = 32; off > 0; off >>= 1) {
        umin = fminf(umin, __shfl_down(umin, off));
        umax = fmaxf(umax, __shfl_down(umax, off));
        vmin = fminf(vmin, __shfl_down(vmin, off));
        vmax = fmaxf(vmax, __shfl_down(vmax, off));
    }
    __shared__ float4 sm[4];
    int lane = threadIdx.x & 63, wid = threadIdx.x >> 6;
    if (lane == 0) sm[wid] = make_float4(umin, umax, vmin, vmax);
    __syncthreads();
    if (threadIdx.x == 0) {
        float4 r = sm[0];
        for (int k = 1; k < 4; ++k) {
            r.x = fminf(r.x, sm[k].x); r.y = fmaxf(r.y, sm[k].y);
            r.z = fminf(r.z, sm[k].z); r.w = fmaxf(r.w, sm[k].w);
        }
        partial[blockIdx.x] = r;
    }
}

__global__ void k_minmax2(const float4* __restrict__ partial, float* __restrict__ sc) {
    float4 p = partial[threadIdx.x];
    #pragma unroll
    for (int off = 32; off > 0; off >>= 1) {
        p.x = fminf(p.x, __shfl_down(p.x, off));
        p.y = fmaxf(p.y, __shfl_down(p.y, off));
        p.z = fminf(p.z, __shfl_down(p.z, off));
        p.w = fmaxf(p.w, __shfl_down(p.w, off));
    }
    __shared__ float4 sm[2];
    if ((threadIdx.x & 63) == 0) sm[threadIdx.x >> 6] = p;
    __syncthreads();
    if (threadIdx.x == 0) {
        sc[0] = fminf(sm[0].x, sm[1].x);
        sc[1] = fmaxf(sm[0].y, sm[1].y);
        sc[2] = fminf(sm[0].z, sm[1].z);
        sc[3] = fmaxf(sm[0].w, sm[1].w);
    }
}

__global__ void k_final(const float* __restrict__ blur, const float* __restrict__ x,
                        const float* __restrict__ sc, float* __restrict__ out) {
    int idx = blockIdx.x * blockDim.x + threadIdx.x;
    if (idx >= BB*NPIX) return;
    int b = idx / NPIX;
    int p = idx - b*NPIX;
    float umin = sc[0], umax = sc[1], vmin = sc[2], vmax = sc[3];
    float u = blur[(size_t)b*2*NPIX + p];
    float v = blur[(size_t)b*2*NPIX + NPIX + p];
    u = fminf(fmaxf((u - umin) / (umax - umin + 1e-6f), 0.f), 1.f) * 0.872f - 0.436f;
    v = fminf(fmaxf((v - vmin) / (vmax - vmin + 1e-6f), 0.f), 1.f) * 1.23f  - 0.615f;
    float y = x[(size_t)b*NPIX + p];
    out[(size_t)(b*3+0)*NPIX + p] = y + 1.14f*v;
    out[(size_t)(b*3+1)*NPIX + p] = y - 0.396f*u - 0.581f*v;
    out[(size_t)(b*3+2)*NPIX + p] = y + 2.029f*u;
}

// ---------------------------------------------------------------------------
extern "C" void kernel_launch(void* const* d_in, const int* in_sizes, int n_in,
                              void* d_out, int out_size, void* d_ws, size_t ws_size,
                              hipStream_t stream) {
    const float* x  = (const float*)d_in[0];
    const float* w1 = (const float*)d_in[1];
    const float* b1 = (const float*)d_in[2];
    const float* w2 = (const float*)d_in[3];
    const float* b2 = (const float*)d_in[4];
    const float* w3 = (const float*)d_in[5];
    const float* b3 = (const float*)d_in[6];
    float* out = (float*)d_out;
    char* ws = (char*)d_ws;

    // Workspace layout (bytes, 16-aligned). Region X time-shared:
    //   [k_feat..k_conv1]  f2 channels-last bf16 (141,557,760 B)
    //   [k_conv2..]        c2out @ X+0, c3out @ X+24e6, blur @ X+32e6
    const size_t POOLED_OFF = 0;                      // 17,794,944
    const size_t X_OFF      = 17795072;
    const size_t Y_OFF      = X_OFF + 141557760;      // c1o bf16: 35,389,440
    const size_t AP_OFF     = Y_OFF + 35389440;       // apack bf16: 204,800
    const size_t WT2_OFF    = AP_OFF + 409600;        // 9,216
    const size_t WT3_OFF    = WT2_OFF + 9216;         // 3,200
    const size_t PART_OFF   = WT3_OFF + 3328;         // 128 * 16
    const size_t SC_OFF     = PART_OFF + 2048;        // 16
    const size_t ZP_OFF     = SC_OFF + 256;           // 4,096 zero page

    float*  pooled = (float*)(ws + POOLED_OFF);
    short*  f2     = (short*)(ws + X_OFF);
    float*  c2o    = (float*)(ws + X_OFF);
    float*  c3o    = (float*)(ws + X_OFF + 24000000);
    float*  blur   = (float*)(ws + X_OFF + 32000000);
    short*  c1o    = (short*)(ws + Y_OFF);
    short*  apack  = (short*)(ws + AP_OFF);
    float*  wT2    = (float*)(ws + WT2_OFF);
    float*  wT3    = (float*)(ws + WT3_OFF);
    float4* part   = (float4*)(ws + PART_OFF);
    float*  sc     = (float*)(ws + SC_OFF);
    float*  zp     = (float*)(ws + ZP_OFF);

    k_wprep<<<512, 256, 0, stream>>>(w1, w2, w3, apack, wT2, wT3, zp);

    dim3 pg((WP + 15)/16, (HP + 15)/16, BB);   // 33 x 17 x 4
    k_pool<<<pg, 256, 0, stream>>>(x, pooled);

    dim3 fg(WW/16, (HH + 15)/16, BB);          // 32 x 17 x 4
    k_feat<<<fg, 256, 0, stream>>>(pooled, f2);

    dim3 cg1(WW/128, (HH + 3)/4, BB);          // 4 x 68 x 4
    k_conv1<<<cg1, 256, 0, stream>>>(f2, apack, b1, c1o, zp);

    dim3 cg(WW/16, (HH + 15)/16, BB);          // 32 x 17 x 4
    k_conv2<<<cg, 256, 0, stream>>>(c1o, wT2, b2, c2o);
    k_conv3<<<cg, 256, 0, stream>>>(c2o, wT3, b3, c3o);

    k_bilat<<<(BB*NPIX + 255)/256, 256, 0, stream>>>(c3o, x, blur);
    k_minmax1<<<128, 256, 0, stream>>>(blur, part);
    k_minmax2<<<1, 128, 0, stream>>>(part, sc);
    k_final<<<(BB*NPIX + 255)/256, 256, 0, stream>>>(blur, x, sc, out);
}